// Round 8
// baseline (2779.558 us; speedup 1.0000x reference)
//
#include <hip/hip_runtime.h>
#include <hip/hip_bf16.h>
#include <math.h>

typedef __bf16 bf16_t;
typedef __bf16 bf16x4v __attribute__((ext_vector_type(4)));
typedef __bf16 bf16x8v __attribute__((ext_vector_type(8)));
typedef float  f32x4v  __attribute__((ext_vector_type(4)));

#define MFMA(a,b,c) __builtin_amdgcn_mfma_f32_16x16x32_bf16(a,b,c,0,0,0)

constexpr int B_ = 8, N_ = 1024, IN_ = 2048, DIM_ = 512, H_ = 8, DH_ = 64;
constexpr int DEPTH_ = 2, E_ = 4, C_ = 10, S_ = 1025;
constexpr int SPK = 1088;       // padded key/value seq len (17*64)
constexpr int MP = 8320;        // padded row count for activations (65*128)
constexpr int MROWS = B_ * S_;  // 8200 valid rows per expert
constexpr size_t KV_SLICE = (size_t)B_ * H_ * SPK * DH_;  // one expert's v
// DH^-0.5 * log2(e): folded into Q at the qkv epilogue (R6: kills 32 v_mul
// per thread per K-tile in attention; softmax math unchanged up to rounding)
#define CL2E 0.18033688011111772f

// ---------------------------------------------------------------- async copy
__device__ __forceinline__ void async16(const void* g, void* l) {
  __builtin_amdgcn_global_load_lds((const __attribute__((address_space(1))) void*)g,
                                   (__attribute__((address_space(3))) void*)l, 16, 0, 0);
}

// ------------------------------------------------------- shared GEMM mainloop
// C[128x128] tile = A[128xK] * B^T[128xK]^T.  Both operands stored [rows][K]
// (weights pre-transposed). 4 waves in 2x2; each wave 64x64 via 4x4 MFMAs.
// SINGLE-buffer, 2-barrier schedule (R5 post-mortem: explicit LDS dbuf is a
// net LOSS -- 16->32 KB LDS cuts occupancy, prefetch churns L2, proj
// 119->155 us.  Implicit overlap across co-resident blocks hides the staging
// latency; matches learn_hip m99/m100/m132).  R7 post-mortem: the swapped
// epilogue raised VGPR 84->96 -> occupancy 24.7->18.5% -> proj 119->135 us;
// callers now declare __launch_bounds__(256, 6) (6 waves/EU, VGPR cap ~85).
// LDS chunk-rotation swizzle: slot s of row R holds global 16B chunk
// (s - (R>>1)) & 3 -> conflict-free reads (SQ_LDS_BANK_CONFLICT = 0).
// SW=true (default): operands SWAPPED -- MFMA(bfr, af) -- so the C-frag is
// TRANSPOSED: acc[mt][nt][r]: row = RB + mt*16 + fr, col = CB + nt*16 + q4*4
// + r.  Each lane's 4 regs = 4 consecutive COLUMNS -> epilogues pack vec4
// stores.  SW=false: legacy orientation (row = RB + mt*16 + q4*4 + r,
// col = CB + nt*16 + fr) used by the V gemm.
template <bool SW>
__device__ __forceinline__ void gemm_core(const bf16_t* __restrict__ A,
                                          const bf16_t* __restrict__ Bm, int K,
                                          bf16_t* As, bf16_t* Bs,
                                          f32x4v acc[4][4]) {
  const int tid  = threadIdx.x;
  const int lane = tid & 63, wave = tid >> 6;
  const int fr = lane & 15, q4 = lane >> 4;
  const int wm = (wave >> 1) * 64, wn = (wave & 1) * 64;
  // staging: wave w fills rows [w*32, w*32+32) of both tiles
  const int srow = wave * 32 + (lane >> 2);
  const int scol = (((lane & 3) - (lane >> 3)) & 3) * 8;   // swizzled chunk
  const int sl   = ((q4 + (fr >> 1)) & 3) * 8;             // read-side slot
  const bf16_t* ga = A  + (size_t)srow * K + scol;
  const bf16_t* gb = Bm + (size_t)srow * K + scol;
  bf16_t* la = As + wave * 1024;  // wave-uniform LDS base; HW adds lane*16B
  bf16_t* lb = Bs + wave * 1024;
  for (int k0 = 0; k0 < K; k0 += 32) {
    async16(ga + k0,          la);
    async16(ga + k0 + 16 * K, la + 512);
    async16(gb + k0,          lb);
    async16(gb + k0 + 16 * K, lb + 512);
    __syncthreads();   // drains vmcnt(0): staged data visible
    bf16x8v af[4], bfr[4];
#pragma unroll
    for (int mt = 0; mt < 4; mt++)
      af[mt] = *(const bf16x8v*)&As[(wm + mt * 16 + fr) * 32 + sl];
#pragma unroll
    for (int nt = 0; nt < 4; nt++)
      bfr[nt] = *(const bf16x8v*)&Bs[(wn + nt * 16 + fr) * 32 + sl];
#pragma unroll
    for (int mt = 0; mt < 4; mt++)
#pragma unroll
      for (int nt = 0; nt < 4; nt++)
        acc[mt][nt] = SW ? MFMA(bfr[nt], af[mt], acc[mt][nt])
                         : MFMA(af[mt], bfr[nt], acc[mt][nt]);
    __syncthreads();   // all reads done before next stage overwrites
  }
}

// swapped-frag epilogue index helper:
// acc[mt][nt][r]: row = rb + mt*16 + fr, col = cb + nt*16 + q4*4 + r
#define EPI2_SETUP()                                                   \
  int lane = threadIdx.x & 63, wave = threadIdx.x >> 6;                \
  int fr = lane & 15, q4 = lane >> 4;                                  \
  int rb = blockIdx.x * 128 + (wave >> 1) * 64;                        \
  int cb = blockIdx.y * 128 + (wave & 1) * 64;

// ----------------------------------------------------------------- converts
__global__ __launch_bounds__(256) void k_cvt(const float* __restrict__ in,
                                             bf16_t* __restrict__ out, int n4) {
  int i = blockIdx.x * blockDim.x + threadIdx.x;
  if (i < n4) {
    float4 v = ((const float4*)in)[i];
    bf16x4v o = {(bf16_t)v.x, (bf16_t)v.y, (bf16_t)v.z, (bf16_t)v.w};
    ((bf16x4v*)out)[i] = o;
  }
}

// in [nmat][K][N] f32 -> out [nmat][N][K] bf16 (K,N multiples of 32)
__global__ __launch_bounds__(256) void k_tcvt(const float* __restrict__ in,
                                              bf16_t* __restrict__ out, int K, int N) {
  __shared__ float tile[32][33];
  size_t mb = (size_t)blockIdx.z * K * N;
  int k0 = blockIdx.y * 32, n0 = blockIdx.x * 32;
  int tx = threadIdx.x, ty = threadIdx.y;
#pragma unroll
  for (int i = 0; i < 32; i += 8)
    tile[ty + i][tx] = in[mb + (size_t)(k0 + ty + i) * N + n0 + tx];
  __syncthreads();
#pragma unroll
  for (int i = 0; i < 32; i += 8)
    out[mb + (size_t)(n0 + ty + i) * K + k0 + tx] = (bf16_t)tile[tx][ty + i];
}

// ------------------------------------------------- proj GEMM (router+experts)
// z=0: router relu -> atomic mean-pool partials into racc[B][DIM]
// z=1..4: expert relu -> t[e][b][1+n][d] (vec4 f32 stores)
__global__ __launch_bounds__(256, 6) void k_gemm_proj(
    const bf16_t* __restrict__ xbf, const bf16_t* __restrict__ wrt,
    const bf16_t* __restrict__ wpt, const float* __restrict__ br,
    const float* __restrict__ bp, float* __restrict__ racc,
    float* __restrict__ t) {
  __shared__ bf16_t As[128 * 32], Bs[128 * 32];
  int z = blockIdx.z;
  const bf16_t* A  = xbf + (size_t)blockIdx.x * 128 * IN_;
  const bf16_t* Bm = (z == 0 ? wrt : wpt + (size_t)(z - 1) * DIM_ * IN_)
                     + (size_t)blockIdx.y * 128 * IN_;
  const float* bias = (z == 0) ? br : bp + (z - 1) * DIM_;
  f32x4v acc[4][4] = {};
  gemm_core<true>(A, Bm, IN_, As, Bs, acc);
  EPI2_SETUP();
  if (z == 0) {
    // all 128 rows of this block belong to batch b = blockIdx.x>>3;
    // reduce relu'd values over the wave's 64 rows (mt x fr), then one
    // atomic per column from the fr==0 lanes.
    int b = blockIdx.x >> 3;
#pragma unroll
    for (int nt = 0; nt < 4; nt++)
#pragma unroll
      for (int r = 0; r < 4; r++) {
        int col = cb + nt * 16 + q4 * 4 + r;
        float p = 0.f;
#pragma unroll
        for (int mt = 0; mt < 4; mt++)
          p += fmaxf(acc[mt][nt][r] + bias[col], 0.f);
#pragma unroll
        for (int o = 1; o < 16; o <<= 1) p += __shfl_xor(p, o, 64);
        if (fr == 0) atomicAdd(&racc[b * DIM_ + col], p);
      }
  } else {
    int e = z - 1;
#pragma unroll
    for (int mt = 0; mt < 4; mt++) {
      int row = rb + mt * 16 + fr;          // always < 8192 (grid.x = 64)
      int b = row >> 10, n = row & 1023;
      float* trow = t + ((size_t)(e * B_ + b) * S_ + 1 + n) * DIM_;
#pragma unroll
      for (int nt = 0; nt < 4; nt++) {
        int col = cb + nt * 16 + q4 * 4;
        f32x4v o;
#pragma unroll
        for (int r = 0; r < 4; r++)
          o[r] = fmaxf(acc[mt][nt][r] + bias[col + r], 0.f);
        *(f32x4v*)&trow[col] = o;
      }
    }
  }
}

__global__ __launch_bounds__(512) void k_cls(const float* __restrict__ cls,
                                             float* __restrict__ t) {
  // block = (e*8+b); s=0 row
  t[(size_t)blockIdx.x * S_ * DIM_ + threadIdx.x] =
      cls[(blockIdx.x >> 3) * DIM_ + threadIdx.x];
}

// ------------------------------------------------------------------ router
__global__ __launch_bounds__(64) void k_router(const float* __restrict__ racc,
                                               const float* __restrict__ Wrf,
                                               const float* __restrict__ brf,
                                               float* __restrict__ gws,
                                               float* __restrict__ outg) {
  __shared__ float lg[8][4];
  int t = threadIdx.x;
  if (t < 32) {
    int b = t >> 2, e = t & 3;
    const float* r = racc + b * DIM_;
    float a = 0.f;
    for (int d = 0; d < DIM_; d++) a += r[d] * Wrf[d * 4 + e];
    lg[b][e] = a * (1.f / N_) + brf[e];
  }
  __syncthreads();
  if (t < 8) {
    int b = t;
    float mx = fmaxf(fmaxf(lg[b][0], lg[b][1]), fmaxf(lg[b][2], lg[b][3]));
    float s = 0.f, g[4];
#pragma unroll
    for (int e = 0; e < 4; e++) { g[e] = __expf(lg[b][e] - mx); s += g[e]; }
#pragma unroll
    for (int e = 0; e < 4; e++) {
      float gv = g[e] / s;
      gws[b * 4 + e] = gv;
      outg[b * 4 + e] = gv;
    }
  }
}

// ------------- layernorm: one wave per row, 4 rows/block (vectorized f32x4)
__global__ __launch_bounds__(256) void k_ln(const float* __restrict__ t,
                                            const float* __restrict__ gg,
                                            const float* __restrict__ bb, int l,
                                            bf16_t* __restrict__ h) {
  int r = blockIdx.x * 4 + (threadIdx.x >> 6);   // global row in [0, E*B*S)
  int lane = threadIdx.x & 63;
  int e = r / MROWS;
  const f32x4v* row = (const f32x4v*)(t + (size_t)r * DIM_);
  f32x4v v0 = row[lane], v1 = row[lane + 64];
  float sum = 0.f, sq = 0.f;
#pragma unroll
  for (int j = 0; j < 4; j++) {
    sum += v0[j] + v1[j];
    sq  += v0[j] * v0[j] + v1[j] * v1[j];
  }
#pragma unroll
  for (int o = 1; o < 64; o <<= 1) {
    sum += __shfl_xor(sum, o, 64);
    sq  += __shfl_xor(sq, o, 64);
  }
  float mean = sum * (1.f / DIM_);
  float var  = sq * (1.f / DIM_) - mean * mean;
  float rstd = rsqrtf(var + 1e-5f);
  const f32x4v* gp = (const f32x4v*)(gg + (size_t)(e * DEPTH_ + l) * DIM_);
  const f32x4v* bp = (const f32x4v*)(bb + (size_t)(e * DEPTH_ + l) * DIM_);
  f32x4v g0 = gp[lane], g1 = gp[lane + 64];
  f32x4v b0 = bp[lane], b1 = bp[lane + 64];
  bf16_t* orow = h + ((size_t)r + (size_t)e * (MP - MROWS)) * DIM_;
  bf16x4v o0, o1;
#pragma unroll
  for (int j = 0; j < 4; j++) {
    o0[j] = (bf16_t)((v0[j] - mean) * rstd * g0[j] + b0[j]);
    o1[j] = (bf16_t)((v1[j] - mean) * rstd * g1[j] + b1[j]);
  }
  ((bf16x4v*)orow)[lane]      = o0;
  ((bf16x4v*)orow)[lane + 64] = o1;
}

__global__ __launch_bounds__(256) void k_lnf(const float* __restrict__ t,
                                             const float* __restrict__ gg,
                                             const float* __restrict__ bb,
                                             float* __restrict__ lat) {
  int eb = blockIdx.x, e = eb >> 3;
  const float* row = t + (size_t)eb * S_ * DIM_;  // s=0 (cls)
  int tid = threadIdx.x;
  float v0 = row[tid], v1 = row[tid + 256];
  float sum = v0 + v1, sq = v0 * v0 + v1 * v1;
  for (int o = 32; o > 0; o >>= 1) {
    sum += __shfl_down(sum, o, 64);
    sq  += __shfl_down(sq, o, 64);
  }
  __shared__ float sb[8];
  int lane = tid & 63, wave = tid >> 6;
  if (lane == 0) { sb[wave * 2] = sum; sb[wave * 2 + 1] = sq; }
  __syncthreads();
  float ts = sb[0] + sb[2] + sb[4] + sb[6];
  float tq = sb[1] + sb[3] + sb[5] + sb[7];
  float mean = ts * (1.f / DIM_);
  float var  = tq * (1.f / DIM_) - mean * mean;
  float rstd = rsqrtf(var + 1e-5f);
  lat[(size_t)eb * DIM_ + tid]       = (v0 - mean) * rstd * gg[e * DIM_ + tid] + bb[e * DIM_ + tid];
  lat[(size_t)eb * DIM_ + tid + 256] = (v1 - mean) * rstd * gg[e * DIM_ + tid + 256] + bb[e * DIM_ + tid + 256];
}

// -------------------- fused QKV GEMM (zc experts per launch)
// y in [0,4):  q -- swapped frag, vec4 row-major store into qo[e][MP][DIM],
//              PRE-SCALED by CL2E (consumed only by attention; saves the
//              per-score scale there).
// y in [4,8):  k -- swapped frag, vec4 ROW-MAJOR store into kb[esub][MP][DIM].
// y in [8,12): v -- legacy orientation (A = V-channel weight rows, Bm =
//              activation rows) so the V^T store (vb[dh][s]) is contiguous.
__global__ __launch_bounds__(256, 6) void k_gemm_qkv(
    const bf16_t* __restrict__ h, const bf16_t* __restrict__ wt,
    const float* __restrict__ bias, int ebase, int l, bf16_t* __restrict__ qo,
    bf16_t* __restrict__ kb, bf16_t* __restrict__ vb) {
  __shared__ bf16_t As[128 * 32], Bs[128 * 32];
  int esub = blockIdx.z, e = ebase + esub;
  const float* bp = bias + (size_t)(e * DEPTH_ + l) * (3 * DIM_);
  f32x4v acc[4][4] = {};
  if (blockIdx.y < 8) {
    const bf16_t* A  = h + ((size_t)e * MP + blockIdx.x * 128) * DIM_;
    const bf16_t* Bm = wt + ((size_t)(e * DEPTH_ + l) * (3 * DIM_) + blockIdx.y * 128) * DIM_;
    gemm_core<true>(A, Bm, DIM_, As, Bs, acc);
    EPI2_SETUP();
    bf16_t* dst;
    int coff;
    float scale;
    if (blockIdx.y < 4) { dst = qo + (size_t)e * MP * DIM_;    coff = 0;   scale = CL2E; }
    else                { dst = kb + (size_t)esub * MP * DIM_; coff = 512; scale = 1.f; }
#pragma unroll
    for (int mt = 0; mt < 4; mt++) {
      int row = rb + mt * 16 + fr;
      if (row < MROWS) {
#pragma unroll
        for (int nt = 0; nt < 4; nt++) {
          int col = cb + nt * 16 + q4 * 4;
          bf16x4v o;
#pragma unroll
          for (int r = 0; r < 4; r++)
            o[r] = (bf16_t)((acc[mt][nt][r] + bp[col + r]) * scale);
          *(bf16x4v*)&dst[(size_t)row * DIM_ + (col - coff)] = o;
        }
      }
    }
  } else {
    size_t slice = (size_t)esub * KV_SLICE;
    int yv = blockIdx.y - 8;
    const bf16_t* A  = wt + ((size_t)(e * DEPTH_ + l) * (3 * DIM_) + 1024 + yv * 128) * DIM_;
    const bf16_t* Bm = h + ((size_t)e * MP + blockIdx.x * 128) * DIM_;
    gemm_core<false>(A, Bm, DIM_, As, Bs, acc);
    // legacy roles: frag row -> V channel, frag col -> token row
    int lane = threadIdx.x & 63, wave = threadIdx.x >> 6;
    int wb = yv * 128 + (wave >> 1) * 64 + ((lane >> 4) << 2);
    int sb = blockIdx.x * 128 + (wave & 1) * 64 + (lane & 15);
#pragma unroll
    for (int mt = 0; mt < 4; mt++)
#pragma unroll
      for (int nt = 0; nt < 4; nt++)
#pragma unroll
        for (int r = 0; r < 4; r++) {
          int srow = sb + nt * 16;
          if (srow < MROWS) {
            int wch = wb + mt * 16 + r;        // 0..511 within V region
            float v = acc[mt][nt][r] + bp[1024 + wch];
            int b = srow / S_, s = srow - b * S_;
            int hh = wch >> 6, dh = wch & 63;
            vb[slice + ((size_t)b * H_ + hh) * DH_ * SPK + (size_t)dh * SPK + s] = (bf16_t)v;
          }
        }
  }
}

// --------------------------------- flash attention (zc experts per launch)
// 1-D grid, XCD-aware decode (T1): HW assigns block i -> XCD i%8; we give
// each XCD whole (z,h) groups of 9 qt-blocks so a group's K/V slice (278 KB)
// is fetched into ONE XCD L2 and reused by all 9 blocks (R6: FETCH was 8x
// over-fetched with the default round-robin mapping).  Work per XCD is equal.
// Q is read from ob (row-major [e][MP][DIM], PRE-SCALED by CL2E) and O is
// written IN PLACE.  K row-major [esub][MP][DIM]; V [esub][b][h][dh][SPK].
// qt<8: 128 q-rows (tokens 1..1024).  qt==8: cls row via split-K across the
// 4 waves.  K/V staged via global_load_lds, double-buffered; kt-loop is
// 2x-unrolled with STATIC buffer bases; masked tile 16 peeled to epilogue
// (hot loop has no mask code and no runtime buffer index).
// S^T trick: QK^T computed with operands SWAPPED -- MFMA(kf, qf).
// No max-subtraction (|s| <~ 2); rowsum via ones-MFMA.  K rows beyond MROWS
// are garbage but masked by ASSIGNMENT (NaN-safe); V padding is zeroed once.
__global__ __launch_bounds__(256, 3) void k_attn(bf16_t* ob,
                                                 const bf16_t* __restrict__ kb,
                                                 const bf16_t* __restrict__ vb,
                                                 int ebase) {
  __shared__ bf16_t P[4][32 * 72];
  __shared__ bf16_t Ks[2][4096], Vs[2][4096];
  // XCD-aware decode: i%8 = XCD, groups of 9 consecutive j on one XCD
  int zc8 = (int)gridDim.x / 72;         // 8*zc  (grid = 576*zc)
  int xcd = blockIdx.x & 7;
  int j   = blockIdx.x >> 3;
  int grp = xcd * zc8 + j / 9;           // (z,h) group id
  int qt  = j % 9;
  int hh  = grp & 7;
  int z   = grp >> 3;                    // esub*8 + b
  int esub = z >> 3, b = z & 7;
  int e = ebase + esub;
  size_t slice = (size_t)esub * KV_SLICE;
  const bf16_t* Q = ob + ((size_t)e * MP + (size_t)b * S_) * DIM_ + hh * DH_;
  const bf16_t* K = kb + ((size_t)esub * MP + (size_t)b * S_) * DIM_ + hh * DH_;
  const bf16_t* V = vb + slice + ((size_t)b * H_ + hh) * DH_ * SPK;
  int lane = threadIdx.x & 63, wave = threadIdx.x >> 6;
  int fr = lane & 15, q4 = lane >> 4;
  int sw = fr & 7;                  // per-lane read-side swizzle
  bf16_t* Pw = &P[wave][0];

  bf16x8v ones;
#pragma unroll
  for (int jj = 0; jj < 8; jj++) ones[jj] = (bf16_t)1.0f;

  if (qt == 8) {
    // ---------------- cls row (s=0): per-wave key-tile subsets, no LDS stage
    bf16x8v qf0[2];
#pragma unroll
    for (int kk = 0; kk < 2; kk++)
      qf0[kk] = *(const bf16x8v*)&Q[q4 * 8 + kk * 32];
    f32x4v O1[4] = {};
    f32x4v l1 = {};
    for (int kt = wave; kt < 17; kt += 4) {
      int ks = kt * 64;
      f32x4v sc[4] = {};
#pragma unroll
      for (int nt = 0; nt < 4; nt++) {
        bf16x8v kf0 = *(const bf16x8v*)&K[(size_t)(ks + nt * 16 + fr) * DIM_ + q4 * 8];
        bf16x8v kf1 = *(const bf16x8v*)&K[(size_t)(ks + nt * 16 + fr) * DIM_ + q4 * 8 + 32];
        sc[nt] = MFMA(kf0, qf0[0], sc[nt]);
        sc[nt] = MFMA(kf1, qf0[1], sc[nt]);
      }
      if (ks + 64 > S_) {
#pragma unroll
        for (int nt = 0; nt < 4; nt++)
#pragma unroll
          for (int c = 0; c < 4; c++)
            if (ks + nt * 16 + q4 * 4 + c >= S_) sc[nt][c] = -1e30f;
      }
#pragma unroll
      for (int nt = 0; nt < 4; nt++) {
        bf16x4v pk;
#pragma unroll
        for (int c = 0; c < 4; c++)
          pk[c] = (bf16_t)__builtin_amdgcn_exp2f(sc[nt][c]);
        *(bf16x4v*)&Pw[fr * 72 + nt * 16 + q4 * 4] = pk;
      }
#pragma unroll
      for (int kk = 0; kk < 2; kk++) {
        bf16x8v pa = *(const bf16x8v*)&Pw[fr * 72 + q4 * 8 + kk * 32];
        l1 = MFMA(pa, ones, l1);
#pragma unroll
        for (int nt = 0; nt < 4; nt++) {
          bf16x8v vf = *(const bf16x8v*)&V[(size_t)(nt * 16 + fr) * SPK + ks + (q4 + kk * 4) * 8];
          O1[nt] = MFMA(pa, vf, O1[nt]);
        }
      }
    }
    // combine waves: only D-row 0 (lanes q4==0, component c==0) is the cls row
    __syncthreads();
    float* comb = (float*)&P[0][0];   // [4][65] f32 overlay (fits in P[0])
    if (q4 == 0) {
#pragma unroll
      for (int nt = 0; nt < 4; nt++) comb[wave * 65 + nt * 16 + fr] = O1[nt][0];
      if (fr == 0) comb[wave * 65 + 64] = l1[0];
    }
    __syncthreads();
    if (threadIdx.x < 64) {
      int d = threadIdx.x;
      float num = comb[d] + comb[65 + d] + comb[130 + d] + comb[195 + d];
      float den = comb[64] + comb[129] + comb[194] + comb[259];
      ob[((size_t)e * MP + (size_t)b * S_) * DIM_ + hh * DH_ + d] = (bf16_t)(num / den);
    }
    return;
  }

  // per-lane staging sources (two 1024B windows per buffer half)
  int pp0 = wave * 64 + lane, pp1 = 256 + wave * 64 + lane;
  int row0 = pp0 >> 3, ch0 = (pp0 & 7) ^ (row0 & 7);
  int row1 = pp1 >> 3, ch1 = (pp1 & 7) ^ (row1 & 7);
  const bf16_t* gk0 = K + (size_t)row0 * DIM_ + ch0 * 8;
  const bf16_t* gk1 = K + (size_t)row1 * DIM_ + ch1 * 8;
  const bf16_t* gv0 = V + (size_t)row0 * SPK + ch0 * 8;
  const bf16_t* gv1 = V + (size_t)row1 * SPK + ch1 * 8;

#define STAGE_KV(BUF, KS)                                                \
  do {                                                                   \
    async16(gk0 + (size_t)(KS) * DIM_, &Ks[BUF][(wave * 64) * 8]);       \
    async16(gk1 + (size_t)(KS) * DIM_, &Ks[BUF][(256 + wave * 64) * 8]); \
    async16(gv0 + (KS), &Vs[BUF][(wave * 64) * 8]);                      \
    async16(gv1 + (KS), &Vs[BUF][(256 + wave * 64) * 8]);                \
  } while (0)

#define COMP_ATTN(BUF, KS, MASKED)                                            \
  do {                                                                        \
    const bf16_t* Kb = &Ks[BUF][0];                                           \
    const bf16_t* Vb = &Vs[BUF][0];                                           \
    f32x4v sc[2][4] = {};                                                     \
    _Pragma("unroll")                                                         \
    for (int nt = 0; nt < 4; nt++) {                                          \
      int rbase = (nt * 16 + fr) * 8;                                         \
      bf16x8v kf0 = *(const bf16x8v*)&Kb[(rbase + ((q4 + 0) ^ sw)) * 8];      \
      bf16x8v kf1 = *(const bf16x8v*)&Kb[(rbase + ((q4 + 4) ^ sw)) * 8];      \
      _Pragma("unroll")                                                       \
      for (int mt = 0; mt < 2; mt++) {                                        \
        sc[mt][nt] = MFMA(kf0, qf[mt][0], sc[mt][nt]);                        \
        sc[mt][nt] = MFMA(kf1, qf[mt][1], sc[mt][nt]);                        \
      }                                                                       \
    }                                                                         \
    if (MASKED) {                                                             \
      _Pragma("unroll")                                                       \
      for (int nt = 0; nt < 4; nt++)                                          \
        _Pragma("unroll")                                                     \
        for (int c = 0; c < 4; c++)                                           \
          if ((KS) + nt * 16 + q4 * 4 + c >= S_) {                            \
            _Pragma("unroll")                                                 \
            for (int mt = 0; mt < 2; mt++) sc[mt][nt][c] = -1e30f;            \
          }                                                                   \
    }                                                                         \
    _Pragma("unroll")                                                         \
    for (int mt = 0; mt < 2; mt++)                                            \
      _Pragma("unroll")                                                       \
      for (int nt = 0; nt < 4; nt++) {                                        \
        bf16x4v pk;                                                           \
        _Pragma("unroll")                                                     \
        for (int c = 0; c < 4; c++)                                           \
          pk[c] = (bf16_t)__builtin_amdgcn_exp2f(sc[mt][nt][c]);              \
        *(bf16x4v*)&Pw[(mt * 16 + fr) * 72 + nt * 16 + q4 * 4] = pk;          \
      }                                                                       \
    _Pragma("unroll")                                                         \
    for (int kk = 0; kk < 2; kk++) {                                          \
      bf16x8v pa[2];                                                          \
      _Pragma("unroll")                                                       \
      for (int mt = 0; mt < 2; mt++) {                                        \
        pa[mt] = *(const bf16x8v*)&Pw[(mt * 16 + fr) * 72 + q4 * 8 + kk * 32];\
        lacc[mt] = MFMA(pa[mt], ones, lacc[mt]);                              \
      }                                                                       \
      _Pragma("unroll")                                                       \
      for (int nt = 0; nt < 4; nt++) {                                        \
        bf16x8v vf = *(const bf16x8v*)&Vb[((nt * 16 + fr) * 8 +               \
                                           ((q4 + kk * 4) ^ sw)) * 8];        \
        _Pragma("unroll")                                                     \
        for (int mt = 0; mt < 2; mt++)                                        \
          O[mt][nt] = MFMA(pa[mt], vf, O[mt][nt]);                            \
      }                                                                       \
    }                                                                         \
  } while (0)

  bf16x8v qf[2][2];
#pragma unroll
  for (int mt = 0; mt < 2; mt++)
#pragma unroll
    for (int kk = 0; kk < 2; kk++)
      qf[mt][kk] = *(const bf16x8v*)&Q[(size_t)(1 + qt * 128 + wave * 32 + mt * 16 + fr) * DIM_
                                       + q4 * 8 + kk * 32];

  f32x4v O[2][4] = {};
  f32x4v lacc[2] = {};

  // tiles 0..16; loop handles 0..15 (2x-unrolled, static buffers, no mask),
  // tile 16 (the only masked one) is peeled below.
  STAGE_KV(0, 0);
  for (int kt = 0; kt < 16; kt += 2) {
    int ks = kt * 64;
    __syncthreads();               // buf0(t_kt) staged; prior buf1 reads done
    STAGE_KV(1, ks + 64);          // t_{kt+1}, in flight under compute
    COMP_ATTN(0, ks, false);
    __syncthreads();               // buf1 staged; buf0 reads done
    STAGE_KV(0, ks + 128);         // t_{kt+2}; at kt=14 this stages tile 16
    COMP_ATTN(1, ks + 64, false);
  }
  __syncthreads();
  COMP_ATTN(0, 1024, true);        // tile 16, masked

#undef STAGE_KV
#undef COMP_ATTN

#pragma unroll
  for (int mt = 0; mt < 2; mt++)
#pragma unroll
    for (int c = 0; c < 4; c++) {
      int s = 1 + qt * 128 + wave * 32 + mt * 16 + q4 * 4 + c;  // always valid
      float inv = 1.f / lacc[mt][c];
#pragma unroll
      for (int nt = 0; nt < 4; nt++)
        ob[((size_t)e * MP + (size_t)b * S_ + s) * DIM_ + hh * DH_ + nt * 16 + fr]
            = (bf16_t)(O[mt][nt][c] * inv);
    }
}

// ------------------------------------------- GEMM + residual-add (Wo and W2)
__global__ __launch_bounds__(256, 6) void k_gemm_res(
    const bf16_t* __restrict__ abuf, const bf16_t* __restrict__ wt,
    const float* __restrict__ bias, int l, float* __restrict__ t) {
  __shared__ bf16_t As[128 * 32], Bs[128 * 32];
  int e = blockIdx.z;
  const bf16_t* A  = abuf + ((size_t)e * MP + blockIdx.x * 128) * DIM_;
  const bf16_t* Bm = wt + ((size_t)(e * DEPTH_ + l) * DIM_ + blockIdx.y * 128) * DIM_;
  const float* bp = bias + (size_t)(e * DEPTH_ + l) * DIM_;
  f32x4v acc[4][4] = {};
  gemm_core<true>(A, Bm, DIM_, As, Bs, acc);
  EPI2_SETUP();
#pragma unroll
  for (int mt = 0; mt < 4; mt++) {
    int row = rb + mt * 16 + fr;
    if (row < MROWS) {
      float* trow = t + ((size_t)e * MROWS + row) * DIM_;
#pragma unroll
      for (int nt = 0; nt < 4; nt++) {
        int col = cb + nt * 16 + q4 * 4;
        f32x4v o = *(const f32x4v*)&trow[col];
#pragma unroll
        for (int r = 0; r < 4; r++) o[r] += acc[mt][nt][r] + bp[col + r];
        *(f32x4v*)&trow[col] = o;
      }
    }
  }
}

// ----------------------------------------------------------- W1 GEMM + gelu
__global__ __launch_bounds__(256, 6) void k_gemm_gelu(
    const bf16_t* __restrict__ abuf, const bf16_t* __restrict__ wt,
    const float* __restrict__ bias, int l, bf16_t* __restrict__ ub) {
  __shared__ bf16_t As[128 * 32], Bs[128 * 32];
  int e = blockIdx.z;
  const bf16_t* A  = abuf + ((size_t)e * MP + blockIdx.x * 128) * DIM_;
  const bf16_t* Bm = wt + ((size_t)(e * DEPTH_ + l) * DIM_ + blockIdx.y * 128) * DIM_;
  const float* bp = bias + (size_t)(e * DEPTH_ + l) * DIM_;
  f32x4v acc[4][4] = {};
  gemm_core<true>(A, Bm, DIM_, As, Bs, acc);
  EPI2_SETUP();
#pragma unroll
  for (int mt = 0; mt < 4; mt++) {
    int row = rb + mt * 16 + fr;
    if (row < MROWS) {
      bf16_t* urow = ub + ((size_t)e * MP + row) * DIM_;
#pragma unroll
      for (int nt = 0; nt < 4; nt++) {
        int col = cb + nt * 16 + q4 * 4;
        bf16x4v o;
#pragma unroll
        for (int r = 0; r < 4; r++) {
          float v = acc[mt][nt][r] + bp[col + r];
          // jax.nn.gelu tanh form; tanh(u) = 1 - 2/(exp(2u)+1) via fast exp
          float u2 = __expf(1.5957691216057308f * (v + 0.044715f * v * v * v));
          float th = 1.f - 2.f / (u2 + 1.f);
          o[r] = (bf16_t)(0.5f * v * (1.f + th));
        }
        *(bf16x4v*)&urow[col] = o;
      }
    }
  }
}

// ---------------------------------------------------------- head + mixtures
__global__ __launch_bounds__(256) void k_head(const float* __restrict__ lat,
                                              const float* __restrict__ Wh,
                                              const float* __restrict__ bh,
                                              const float* __restrict__ gws,
                                              float* __restrict__ out) {
  int b = blockIdx.x, tid = threadIdx.x;
  for (int d = tid; d < DIM_; d += 256) {
    float a = 0.f;
#pragma unroll
    for (int e = 0; e < 4; e++)
      a += gws[b * 4 + e] * lat[(size_t)(e * B_ + b) * DIM_ + d];
    out[b * DIM_ + d] = a;
  }
  __shared__ float lg[4][10];
  if (tid < 40) {
    int e = tid / 10, c = tid % 10;
    const float* le = lat + (size_t)(e * B_ + b) * DIM_;
    const float* w  = Wh + (size_t)e * DIM_ * C_;
    float a = 0.f;
    for (int d = 0; d < DIM_; d++) a += le[d] * w[d * C_ + c];
    lg[e][c] = a + bh[e * C_ + c];
  }
  __syncthreads();
  if (tid < 10) {
    float a = 0.f;
#pragma unroll
    for (int e = 0; e < 4; e++) a += gws[b * 4 + e] * lg[e][tid];
    out[B_ * DIM_ + b * C_ + tid] = a;
  }
}

// ------------------------------------------------------------------- launch
extern "C" void kernel_launch(void* const* d_in, const int* in_sizes, int n_in,
                              void* d_out, int out_size, void* d_ws, size_t ws_size,
                              hipStream_t stream) {
  const float* x    = (const float*)d_in[0];
  const float* Wr   = (const float*)d_in[1];
  const float* br   = (const float*)d_in[2];
  const float* Wrf  = (const float*)d_in[3];
  const float* brf  = (const float*)d_in[4];
  const float* Wp   = (const float*)d_in[5];
  const float* bp   = (const float*)d_in[6];
  const float* cls  = (const float*)d_in[7];
  const float* ln1g = (const float*)d_in[8];
  const float* ln1b = (const float*)d_in[9];
  const float* Wqkv = (const float*)d_in[10];
  const float* bqkv = (const float*)d_in[11];
  const float* Wo   = (const float*)d_in[12];
  const float* bo   = (const float*)d_in[13];
  const float* ln2g = (const float*)d_in[14];
  const float* ln2b = (const float*)d_in[15];
  const float* W1   = (const float*)d_in[16];
  const float* b1   = (const float*)d_in[17];
  const float* W2   = (const float*)d_in[18];
  const float* b2   = (const float*)d_in[19];
  const float* lnfg = (const float*)d_in[20];
  const float* lnfb = (const float*)d_in[21];
  const float* Wh   = (const float*)d_in[22];
  const float* bh   = (const float*)d_in[23];
  float* out = (float*)d_out;

  // ---- workspace layout (persistent ~154 MiB + union; stream-ordered) ----
  char* w = (char*)d_ws;
  size_t off = 0;
  auto take = [&](size_t bytes) {
    void* p = w + off;
    off += (bytes + 255) & ~(size_t)255;
    return p;
  };
  // persistent region
  bf16_t* wqkv_t = (bf16_t*)take((size_t)E_ * DEPTH_ * 3 * DIM_ * DIM_ * 2);
  bf16_t* wo_t   = (bf16_t*)take((size_t)E_ * DEPTH_ * DIM_ * DIM_ * 2);
  bf16_t* w1_t   = (bf16_t*)take((size_t)E_ * DEPTH_ * DIM_ * DIM_ * 2);
  bf16_t* w2_t   = (bf16_t*)take((size_t)E_ * DEPTH_ * DIM_ * DIM_ * 2);
  float*  tbuf   = (float*)take((size_t)E_ * MROWS * DIM_ * 4);
  bf16_t* hbuf   = (bf16_t*)take((size_t)E_ * MP * DIM_ * 2);
  bf16_t* obuf   = (bf16_t*)take((size_t)E_ * MP * DIM_ * 2);  // q / attn out / W1 out
  float*  racc   = (float*)take((size_t)B_ * DIM_ * 4);
  float*  gws    = (float*)take((size_t)B_ * E_ * 4);
  float*  late   = (float*)take((size_t)E_ * B_ * DIM_ * 4);
  // union region:
  //   view A (dead after k_gemm_proj): x_bf / wr_t / wp_t
  //   view B (rewritten every (l,group)): zc-expert k (row-major) + v
  char* uni = (char*)w + off;
  bf16_t* x_bf = (bf16_t*)(uni);
  bf16_t* wr_t = (bf16_t*)(uni + (size_t)8192 * IN_ * 2);
  bf16_t* wp_t = (bf16_t*)(uni + (size_t)8192 * IN_ * 2 + (size_t)DIM_ * IN_ * 2);
  // pick expert-group width: all 4 experts if workspace allows, else pairs
  size_t kslice_b = (size_t)MP * DIM_ * 2;   // bytes per expert k (row-major)
  size_t vslice_b = KV_SLICE * 2;            // bytes per expert v
  size_t need_full = off + 4 * (kslice_b + vslice_b);
  int zc = (ws_size >= need_full) ? 4 : 2;
  bf16_t* kbuf = (bf16_t*)(uni);
  bf16_t* vbuf = (bf16_t*)(uni + (size_t)zc * kslice_b);
  (void)in_sizes; (void)n_in; (void)out_size;

  // input + weight conversion (weights transposed to [N][K] bf16)
  int n4 = 8192 * IN_ / 4;
  k_cvt<<<(n4 + 255) / 256, 256, 0, stream>>>(x, x_bf, n4);
  dim3 tb(32, 8);
  k_tcvt<<<dim3(DIM_ / 32, IN_ / 32, 1), tb, 0, stream>>>(Wr, wr_t, IN_, DIM_);
  k_tcvt<<<dim3(DIM_ / 32, IN_ / 32, E_), tb, 0, stream>>>(Wp, wp_t, IN_, DIM_);
  k_tcvt<<<dim3(3 * DIM_ / 32, DIM_ / 32, E_ * DEPTH_), tb, 0, stream>>>(Wqkv, wqkv_t, DIM_, 3 * DIM_);
  k_tcvt<<<dim3(DIM_ / 32, DIM_ / 32, E_ * DEPTH_), tb, 0, stream>>>(Wo, wo_t, DIM_, DIM_);
  k_tcvt<<<dim3(DIM_ / 32, DIM_ / 32, E_ * DEPTH_), tb, 0, stream>>>(W1, w1_t, DIM_, DIM_);
  k_tcvt<<<dim3(DIM_ / 32, DIM_ / 32, E_ * DEPTH_), tb, 0, stream>>>(W2, w2_t, DIM_, DIM_);

  // router + expert input projections (z=0 router-pool, z=1..4 experts)
  hipMemsetAsync(racc, 0, (size_t)B_ * DIM_ * 4, stream);
  k_gemm_proj<<<dim3(64, 4, 5), 256, 0, stream>>>(x_bf, wr_t, wp_t, br, bp, racc, tbuf);
  k_cls<<<32, 512, 0, stream>>>(cls, tbuf);
  k_router<<<1, 64, 0, stream>>>(racc, Wrf, brf, gws, out + B_ * DIM_ + B_ * C_);
  // zero v buffer once: its padded s-range [S_, SPK) is never written by the
  // v-GEMM but IS multiplied (by P=0) in attention -- must be finite.
  hipMemsetAsync(vbuf, 0, (size_t)zc * vslice_b, stream);

  for (int l = 0; l < DEPTH_; l++) {
    k_ln<<<MROWS * E_ / 4, 256, 0, stream>>>(tbuf, ln1g, ln1b, l, hbuf);
    for (int eb = 0; eb < E_; eb += zc) {
      k_gemm_qkv<<<dim3(65, 12, zc), 256, 0, stream>>>(hbuf, wqkv_t, bqkv, eb, l,
                                                       obuf, kbuf, vbuf);
      k_attn<<<dim3(576 * zc, 1, 1), 256, 0, stream>>>(obuf, kbuf, vbuf, eb);
    }
    k_gemm_res<<<dim3(65, 4, E_), 256, 0, stream>>>(obuf, wo_t, bo, l, tbuf);
    k_ln<<<MROWS * E_ / 4, 256, 0, stream>>>(tbuf, ln2g, ln2b, l, hbuf);
    k_gemm_gelu<<<dim3(65, 4, E_), 256, 0, stream>>>(hbuf, w1_t, b1, l, obuf);
    k_gemm_res<<<dim3(65, 4, E_), 256, 0, stream>>>(obuf, w2_t, b2, l, tbuf);
  }
  k_lnf<<<32, 256, 0, stream>>>(tbuf, lnfg, lnfb, late);
  k_head<<<8, 256, 0, stream>>>(late, Wh, bh, gws, out);
}

// Round 9
// 1143.242 us; speedup vs baseline: 2.4313x; 2.4313x over previous
//
#include <hip/hip_runtime.h>
#include <hip/hip_bf16.h>
#include <math.h>

typedef __bf16 bf16_t;
typedef __bf16 bf16x4v __attribute__((ext_vector_type(4)));
typedef __bf16 bf16x8v __attribute__((ext_vector_type(8)));
typedef float  f32x4v  __attribute__((ext_vector_type(4)));

#define MFMA(a,b,c) __builtin_amdgcn_mfma_f32_16x16x32_bf16(a,b,c,0,0,0)

constexpr int B_ = 8, N_ = 1024, IN_ = 2048, DIM_ = 512, H_ = 8, DH_ = 64;
constexpr int DEPTH_ = 2, E_ = 4, C_ = 10, S_ = 1025;
constexpr int SPK = 1088;       // padded key/value seq len (17*64)
constexpr int MP = 8320;        // padded row count for activations (65*128)
constexpr int MROWS = B_ * S_;  // 8200 valid rows per expert
constexpr size_t KV_SLICE = (size_t)B_ * H_ * SPK * DH_;  // one expert's v
// DH^-0.5 * log2(e): folded into Q at the qkv epilogue (R6: kills 32 v_mul
// per thread per K-tile in attention; softmax math unchanged up to rounding)
#define CL2E 0.18033688011111772f

// ---------------------------------------------------------------- async copy
__device__ __forceinline__ void async16(const void* g, void* l) {
  __builtin_amdgcn_global_load_lds((const __attribute__((address_space(1))) void*)g,
                                   (__attribute__((address_space(3))) void*)l, 16, 0, 0);
}

// ------------------------------------------------------- shared GEMM mainloop
// C[128x128] tile = A[128xK] * B^T[128xK]^T.  Both operands stored [rows][K]
// (weights pre-transposed). 4 waves in 2x2; each wave 64x64 via 4x4 MFMAs.
// SINGLE-buffer, 2-barrier schedule (R5: explicit LDS dbuf is a net LOSS --
// occupancy + L2 churn; implicit overlap across co-resident blocks hides the
// staging latency; matches learn_hip m99/m100/m132).
// R8 post-mortem: __launch_bounds__(256,6) (VGPR cap ~85) forced the ~96-VGPR
// working set (acc alone = 64) into scratch: VGPR 40, WRITE_SIZE 1.4 GB,
// proj 481 us.  NEVER cap below the accumulator footprint.  Occupancy bins
// quantize at VGPR 64/128/256, so 84 vs 96 is the SAME bin -- the R7 proj
// delta was FETCH (+17 MB, write RFO on partial-line stores), not occupancy.
// LDS chunk-rotation swizzle: slot s of row R holds global 16B chunk
// (s - (R>>1)) & 3 -> conflict-free reads (SQ_LDS_BANK_CONFLICT = 0).
// SW=true (default): operands SWAPPED -- MFMA(bfr, af) -- so the C-frag is
// TRANSPOSED: acc[mt][nt][r]: row = RB + mt*16 + fr, col = CB + nt*16 + q4*4
// + r.  Each lane's 4 regs = 4 consecutive COLUMNS -> epilogues pack vec4
// stores.  SW=false: legacy orientation (row = RB + mt*16 + q4*4 + r,
// col = CB + nt*16 + fr) used by the V gemm.
template <bool SW>
__device__ __forceinline__ void gemm_core(const bf16_t* __restrict__ A,
                                          const bf16_t* __restrict__ Bm, int K,
                                          bf16_t* As, bf16_t* Bs,
                                          f32x4v acc[4][4]) {
  const int tid  = threadIdx.x;
  const int lane = tid & 63, wave = tid >> 6;
  const int fr = lane & 15, q4 = lane >> 4;
  const int wm = (wave >> 1) * 64, wn = (wave & 1) * 64;
  // staging: wave w fills rows [w*32, w*32+32) of both tiles
  const int srow = wave * 32 + (lane >> 2);
  const int scol = (((lane & 3) - (lane >> 3)) & 3) * 8;   // swizzled chunk
  const int sl   = ((q4 + (fr >> 1)) & 3) * 8;             // read-side slot
  const bf16_t* ga = A  + (size_t)srow * K + scol;
  const bf16_t* gb = Bm + (size_t)srow * K + scol;
  bf16_t* la = As + wave * 1024;  // wave-uniform LDS base; HW adds lane*16B
  bf16_t* lb = Bs + wave * 1024;
  for (int k0 = 0; k0 < K; k0 += 32) {
    async16(ga + k0,          la);
    async16(ga + k0 + 16 * K, la + 512);
    async16(gb + k0,          lb);
    async16(gb + k0 + 16 * K, lb + 512);
    __syncthreads();   // drains vmcnt(0): staged data visible
    bf16x8v af[4], bfr[4];
#pragma unroll
    for (int mt = 0; mt < 4; mt++)
      af[mt] = *(const bf16x8v*)&As[(wm + mt * 16 + fr) * 32 + sl];
#pragma unroll
    for (int nt = 0; nt < 4; nt++)
      bfr[nt] = *(const bf16x8v*)&Bs[(wn + nt * 16 + fr) * 32 + sl];
#pragma unroll
    for (int mt = 0; mt < 4; mt++)
#pragma unroll
      for (int nt = 0; nt < 4; nt++)
        acc[mt][nt] = SW ? MFMA(bfr[nt], af[mt], acc[mt][nt])
                         : MFMA(af[mt], bfr[nt], acc[mt][nt]);
    __syncthreads();   // all reads done before next stage overwrites
  }
}

// swapped-frag epilogue index helper:
// acc[mt][nt][r]: row = rb + mt*16 + fr, col = cb + nt*16 + q4*4 + r
#define EPI2_SETUP()                                                   \
  int lane = threadIdx.x & 63, wave = threadIdx.x >> 6;                \
  int fr = lane & 15, q4 = lane >> 4;                                  \
  int rb = blockIdx.x * 128 + (wave >> 1) * 64;                        \
  int cb = blockIdx.y * 128 + (wave & 1) * 64;

// ----------------------------------------------------------------- converts
__global__ __launch_bounds__(256) void k_cvt(const float* __restrict__ in,
                                             bf16_t* __restrict__ out, int n4) {
  int i = blockIdx.x * blockDim.x + threadIdx.x;
  if (i < n4) {
    float4 v = ((const float4*)in)[i];
    bf16x4v o = {(bf16_t)v.x, (bf16_t)v.y, (bf16_t)v.z, (bf16_t)v.w};
    ((bf16x4v*)out)[i] = o;
  }
}

// in [nmat][K][N] f32 -> out [nmat][N][K] bf16 (K,N multiples of 32)
__global__ __launch_bounds__(256) void k_tcvt(const float* __restrict__ in,
                                              bf16_t* __restrict__ out, int K, int N) {
  __shared__ float tile[32][33];
  size_t mb = (size_t)blockIdx.z * K * N;
  int k0 = blockIdx.y * 32, n0 = blockIdx.x * 32;
  int tx = threadIdx.x, ty = threadIdx.y;
#pragma unroll
  for (int i = 0; i < 32; i += 8)
    tile[ty + i][tx] = in[mb + (size_t)(k0 + ty + i) * N + n0 + tx];
  __syncthreads();
#pragma unroll
  for (int i = 0; i < 32; i += 8)
    out[mb + (size_t)(n0 + ty + i) * K + k0 + tx] = (bf16_t)tile[tx][ty + i];
}

// ------------------------------------------------- proj GEMM (router+experts)
// z=0: router relu -> atomic mean-pool partials into racc[B][DIM]
// z=1..4: expert relu -> t[e][b][1+n][d] (vec4 f32 NONTEMPORAL stores --
// pure-store output; nt skips the L2 read-for-ownership on partial lines)
__global__ __launch_bounds__(256) void k_gemm_proj(
    const bf16_t* __restrict__ xbf, const bf16_t* __restrict__ wrt,
    const bf16_t* __restrict__ wpt, const float* __restrict__ br,
    const float* __restrict__ bp, float* __restrict__ racc,
    float* __restrict__ t) {
  __shared__ bf16_t As[128 * 32], Bs[128 * 32];
  int z = blockIdx.z;
  const bf16_t* A  = xbf + (size_t)blockIdx.x * 128 * IN_;
  const bf16_t* Bm = (z == 0 ? wrt : wpt + (size_t)(z - 1) * DIM_ * IN_)
                     + (size_t)blockIdx.y * 128 * IN_;
  const float* bias = (z == 0) ? br : bp + (z - 1) * DIM_;
  f32x4v acc[4][4] = {};
  gemm_core<true>(A, Bm, IN_, As, Bs, acc);
  EPI2_SETUP();
  if (z == 0) {
    // all 128 rows of this block belong to batch b = blockIdx.x>>3;
    // reduce relu'd values over the wave's 64 rows (mt x fr), then one
    // atomic per column from the fr==0 lanes.
    int b = blockIdx.x >> 3;
#pragma unroll
    for (int nt = 0; nt < 4; nt++)
#pragma unroll
      for (int r = 0; r < 4; r++) {
        int col = cb + nt * 16 + q4 * 4 + r;
        float p = 0.f;
#pragma unroll
        for (int mt = 0; mt < 4; mt++)
          p += fmaxf(acc[mt][nt][r] + bias[col], 0.f);
#pragma unroll
        for (int o = 1; o < 16; o <<= 1) p += __shfl_xor(p, o, 64);
        if (fr == 0) atomicAdd(&racc[b * DIM_ + col], p);
      }
  } else {
    int e = z - 1;
#pragma unroll
    for (int mt = 0; mt < 4; mt++) {
      int row = rb + mt * 16 + fr;          // always < 8192 (grid.x = 64)
      int b = row >> 10, n = row & 1023;
      float* trow = t + ((size_t)(e * B_ + b) * S_ + 1 + n) * DIM_;
#pragma unroll
      for (int nt = 0; nt < 4; nt++) {
        int col = cb + nt * 16 + q4 * 4;
        f32x4v o;
#pragma unroll
        for (int r = 0; r < 4; r++)
          o[r] = fmaxf(acc[mt][nt][r] + bias[col + r], 0.f);
        __builtin_nontemporal_store(o, (f32x4v*)&trow[col]);
      }
    }
  }
}

__global__ __launch_bounds__(512) void k_cls(const float* __restrict__ cls,
                                             float* __restrict__ t) {
  // block = (e*8+b); s=0 row
  t[(size_t)blockIdx.x * S_ * DIM_ + threadIdx.x] =
      cls[(blockIdx.x >> 3) * DIM_ + threadIdx.x];
}

// ------------------------------------------------------------------ router
__global__ __launch_bounds__(64) void k_router(const float* __restrict__ racc,
                                               const float* __restrict__ Wrf,
                                               const float* __restrict__ brf,
                                               float* __restrict__ gws,
                                               float* __restrict__ outg) {
  __shared__ float lg[8][4];
  int t = threadIdx.x;
  if (t < 32) {
    int b = t >> 2, e = t & 3;
    const float* r = racc + b * DIM_;
    float a = 0.f;
    for (int d = 0; d < DIM_; d++) a += r[d] * Wrf[d * 4 + e];
    lg[b][e] = a * (1.f / N_) + brf[e];
  }
  __syncthreads();
  if (t < 8) {
    int b = t;
    float mx = fmaxf(fmaxf(lg[b][0], lg[b][1]), fmaxf(lg[b][2], lg[b][3]));
    float s = 0.f, g[4];
#pragma unroll
    for (int e = 0; e < 4; e++) { g[e] = __expf(lg[b][e] - mx); s += g[e]; }
#pragma unroll
    for (int e = 0; e < 4; e++) {
      float gv = g[e] / s;
      gws[b * 4 + e] = gv;
      outg[b * 4 + e] = gv;
    }
  }
}

// ------------- layernorm: one wave per row, 4 rows/block (vectorized f32x4)
__global__ __launch_bounds__(256) void k_ln(const float* __restrict__ t,
                                            const float* __restrict__ gg,
                                            const float* __restrict__ bb, int l,
                                            bf16_t* __restrict__ h) {
  int r = blockIdx.x * 4 + (threadIdx.x >> 6);   // global row in [0, E*B*S)
  int lane = threadIdx.x & 63;
  int e = r / MROWS;
  const f32x4v* row = (const f32x4v*)(t + (size_t)r * DIM_);
  f32x4v v0 = row[lane], v1 = row[lane + 64];
  float sum = 0.f, sq = 0.f;
#pragma unroll
  for (int j = 0; j < 4; j++) {
    sum += v0[j] + v1[j];
    sq  += v0[j] * v0[j] + v1[j] * v1[j];
  }
#pragma unroll
  for (int o = 1; o < 64; o <<= 1) {
    sum += __shfl_xor(sum, o, 64);
    sq  += __shfl_xor(sq, o, 64);
  }
  float mean = sum * (1.f / DIM_);
  float var  = sq * (1.f / DIM_) - mean * mean;
  float rstd = rsqrtf(var + 1e-5f);
  const f32x4v* gp = (const f32x4v*)(gg + (size_t)(e * DEPTH_ + l) * DIM_);
  const f32x4v* bp = (const f32x4v*)(bb + (size_t)(e * DEPTH_ + l) * DIM_);
  f32x4v g0 = gp[lane], g1 = gp[lane + 64];
  f32x4v b0 = bp[lane], b1 = bp[lane + 64];
  bf16_t* orow = h + ((size_t)r + (size_t)e * (MP - MROWS)) * DIM_;
  bf16x4v o0, o1;
#pragma unroll
  for (int j = 0; j < 4; j++) {
    o0[j] = (bf16_t)((v0[j] - mean) * rstd * g0[j] + b0[j]);
    o1[j] = (bf16_t)((v1[j] - mean) * rstd * g1[j] + b1[j]);
  }
  ((bf16x4v*)orow)[lane]      = o0;
  ((bf16x4v*)orow)[lane + 64] = o1;
}

__global__ __launch_bounds__(256) void k_lnf(const float* __restrict__ t,
                                             const float* __restrict__ gg,
                                             const float* __restrict__ bb,
                                             float* __restrict__ lat) {
  int eb = blockIdx.x, e = eb >> 3;
  const float* row = t + (size_t)eb * S_ * DIM_;  // s=0 (cls)
  int tid = threadIdx.x;
  float v0 = row[tid], v1 = row[tid + 256];
  float sum = v0 + v1, sq = v0 * v0 + v1 * v1;
  for (int o = 32; o > 0; o >>= 1) {
    sum += __shfl_down(sum, o, 64);
    sq  += __shfl_down(sq, o, 64);
  }
  __shared__ float sb[8];
  int lane = tid & 63, wave = tid >> 6;
  if (lane == 0) { sb[wave * 2] = sum; sb[wave * 2 + 1] = sq; }
  __syncthreads();
  float ts = sb[0] + sb[2] + sb[4] + sb[6];
  float tq = sb[1] + sb[3] + sb[5] + sb[7];
  float mean = ts * (1.f / DIM_);
  float var  = tq * (1.f / DIM_) - mean * mean;
  float rstd = rsqrtf(var + 1e-5f);
  lat[(size_t)eb * DIM_ + tid]       = (v0 - mean) * rstd * gg[e * DIM_ + tid] + bb[e * DIM_ + tid];
  lat[(size_t)eb * DIM_ + tid + 256] = (v1 - mean) * rstd * gg[e * DIM_ + tid + 256] + bb[e * DIM_ + tid + 256];
}

// -------------------- fused QKV GEMM (zc experts per launch)
// y in [0,4):  q -- swapped frag, vec4 row-major NT store into qo[e][MP][DIM],
//              PRE-SCALED by CL2E (consumed only by attention; saves the
//              per-score scale there).
// y in [4,8):  k -- swapped frag, vec4 ROW-MAJOR NT store into kb[esub][MP][DIM].
// y in [8,12): v -- legacy orientation (A = V-channel weight rows, Bm =
//              activation rows) so the V^T store (vb[dh][s]) is contiguous.
__global__ __launch_bounds__(256) void k_gemm_qkv(
    const bf16_t* __restrict__ h, const bf16_t* __restrict__ wt,
    const float* __restrict__ bias, int ebase, int l, bf16_t* __restrict__ qo,
    bf16_t* __restrict__ kb, bf16_t* __restrict__ vb) {
  __shared__ bf16_t As[128 * 32], Bs[128 * 32];
  int esub = blockIdx.z, e = ebase + esub;
  const float* bp = bias + (size_t)(e * DEPTH_ + l) * (3 * DIM_);
  f32x4v acc[4][4] = {};
  if (blockIdx.y < 8) {
    const bf16_t* A  = h + ((size_t)e * MP + blockIdx.x * 128) * DIM_;
    const bf16_t* Bm = wt + ((size_t)(e * DEPTH_ + l) * (3 * DIM_) + blockIdx.y * 128) * DIM_;
    gemm_core<true>(A, Bm, DIM_, As, Bs, acc);
    EPI2_SETUP();
    bf16_t* dst;
    int coff;
    float scale;
    if (blockIdx.y < 4) { dst = qo + (size_t)e * MP * DIM_;    coff = 0;   scale = CL2E; }
    else                { dst = kb + (size_t)esub * MP * DIM_; coff = 512; scale = 1.f; }
#pragma unroll
    for (int mt = 0; mt < 4; mt++) {
      int row = rb + mt * 16 + fr;
      if (row < MROWS) {
#pragma unroll
        for (int nt = 0; nt < 4; nt++) {
          int col = cb + nt * 16 + q4 * 4;
          bf16x4v o;
#pragma unroll
          for (int r = 0; r < 4; r++)
            o[r] = (bf16_t)((acc[mt][nt][r] + bp[col + r]) * scale);
          __builtin_nontemporal_store(o, (bf16x4v*)&dst[(size_t)row * DIM_ + (col - coff)]);
        }
      }
    }
  } else {
    size_t slice = (size_t)esub * KV_SLICE;
    int yv = blockIdx.y - 8;
    const bf16_t* A  = wt + ((size_t)(e * DEPTH_ + l) * (3 * DIM_) + 1024 + yv * 128) * DIM_;
    const bf16_t* Bm = h + ((size_t)e * MP + blockIdx.x * 128) * DIM_;
    gemm_core<false>(A, Bm, DIM_, As, Bs, acc);
    // legacy roles: frag row -> V channel, frag col -> token row
    int lane = threadIdx.x & 63, wave = threadIdx.x >> 6;
    int wb = yv * 128 + (wave >> 1) * 64 + ((lane >> 4) << 2);
    int sb = blockIdx.x * 128 + (wave & 1) * 64 + (lane & 15);
#pragma unroll
    for (int mt = 0; mt < 4; mt++)
#pragma unroll
      for (int nt = 0; nt < 4; nt++)
#pragma unroll
        for (int r = 0; r < 4; r++) {
          int srow = sb + nt * 16;
          if (srow < MROWS) {
            int wch = wb + mt * 16 + r;        // 0..511 within V region
            float v = acc[mt][nt][r] + bp[1024 + wch];
            int b = srow / S_, s = srow - b * S_;
            int hh = wch >> 6, dh = wch & 63;
            vb[slice + ((size_t)b * H_ + hh) * DH_ * SPK + (size_t)dh * SPK + s] = (bf16_t)v;
          }
        }
  }
}

// --------------------------------- flash attention (zc experts per launch)
// 1-D grid, XCD-aware decode (T1): HW assigns block i -> XCD i%8; we give
// each XCD whole (z,h) groups of 9 qt-blocks so a group's K/V slice (278 KB)
// is fetched into ONE XCD L2 and reused by all 9 blocks (R6: FETCH was 8x
// over-fetched with the default round-robin mapping).  Work per XCD is equal.
// Q is read from ob (row-major [e][MP][DIM], PRE-SCALED by CL2E) and O is
// written IN PLACE.  K row-major [esub][MP][DIM]; V [esub][b][h][dh][SPK].
// qt<8: 128 q-rows (tokens 1..1024).  qt==8: cls row via split-K across the
// 4 waves.  K/V staged via global_load_lds, double-buffered; kt-loop is
// 2x-unrolled with STATIC buffer bases; masked tile 16 peeled to epilogue
// (hot loop has no mask code and no runtime buffer index).
// S^T trick: QK^T computed with operands SWAPPED -- MFMA(kf, qf).
// No max-subtraction (|s| <~ 2); rowsum via ones-MFMA.  K rows beyond MROWS
// are garbage but masked by ASSIGNMENT (NaN-safe); V padding is zeroed once.
__global__ __launch_bounds__(256, 3) void k_attn(bf16_t* ob,
                                                 const bf16_t* __restrict__ kb,
                                                 const bf16_t* __restrict__ vb,
                                                 int ebase) {
  __shared__ bf16_t P[4][32 * 72];
  __shared__ bf16_t Ks[2][4096], Vs[2][4096];
  // XCD-aware decode: i%8 = XCD, groups of 9 consecutive j on one XCD
  int zc8 = (int)gridDim.x / 72;         // 8*zc  (grid = 576*zc)
  int xcd = blockIdx.x & 7;
  int j   = blockIdx.x >> 3;
  int grp = xcd * zc8 + j / 9;           // (z,h) group id
  int qt  = j % 9;
  int hh  = grp & 7;
  int z   = grp >> 3;                    // esub*8 + b
  int esub = z >> 3, b = z & 7;
  int e = ebase + esub;
  size_t slice = (size_t)esub * KV_SLICE;
  const bf16_t* Q = ob + ((size_t)e * MP + (size_t)b * S_) * DIM_ + hh * DH_;
  const bf16_t* K = kb + ((size_t)esub * MP + (size_t)b * S_) * DIM_ + hh * DH_;
  const bf16_t* V = vb + slice + ((size_t)b * H_ + hh) * DH_ * SPK;
  int lane = threadIdx.x & 63, wave = threadIdx.x >> 6;
  int fr = lane & 15, q4 = lane >> 4;
  int sw = fr & 7;                  // per-lane read-side swizzle
  bf16_t* Pw = &P[wave][0];

  bf16x8v ones;
#pragma unroll
  for (int jj = 0; jj < 8; jj++) ones[jj] = (bf16_t)1.0f;

  if (qt == 8) {
    // ---------------- cls row (s=0): per-wave key-tile subsets, no LDS stage
    bf16x8v qf0[2];
#pragma unroll
    for (int kk = 0; kk < 2; kk++)
      qf0[kk] = *(const bf16x8v*)&Q[q4 * 8 + kk * 32];
    f32x4v O1[4] = {};
    f32x4v l1 = {};
    for (int kt = wave; kt < 17; kt += 4) {
      int ks = kt * 64;
      f32x4v sc[4] = {};
#pragma unroll
      for (int nt = 0; nt < 4; nt++) {
        bf16x8v kf0 = *(const bf16x8v*)&K[(size_t)(ks + nt * 16 + fr) * DIM_ + q4 * 8];
        bf16x8v kf1 = *(const bf16x8v*)&K[(size_t)(ks + nt * 16 + fr) * DIM_ + q4 * 8 + 32];
        sc[nt] = MFMA(kf0, qf0[0], sc[nt]);
        sc[nt] = MFMA(kf1, qf0[1], sc[nt]);
      }
      if (ks + 64 > S_) {
#pragma unroll
        for (int nt = 0; nt < 4; nt++)
#pragma unroll
          for (int c = 0; c < 4; c++)
            if (ks + nt * 16 + q4 * 4 + c >= S_) sc[nt][c] = -1e30f;
      }
#pragma unroll
      for (int nt = 0; nt < 4; nt++) {
        bf16x4v pk;
#pragma unroll
        for (int c = 0; c < 4; c++)
          pk[c] = (bf16_t)__builtin_amdgcn_exp2f(sc[nt][c]);
        *(bf16x4v*)&Pw[fr * 72 + nt * 16 + q4 * 4] = pk;
      }
#pragma unroll
      for (int kk = 0; kk < 2; kk++) {
        bf16x8v pa = *(const bf16x8v*)&Pw[fr * 72 + q4 * 8 + kk * 32];
        l1 = MFMA(pa, ones, l1);
#pragma unroll
        for (int nt = 0; nt < 4; nt++) {
          bf16x8v vf = *(const bf16x8v*)&V[(size_t)(nt * 16 + fr) * SPK + ks + (q4 + kk * 4) * 8];
          O1[nt] = MFMA(pa, vf, O1[nt]);
        }
      }
    }
    // combine waves: only D-row 0 (lanes q4==0, component c==0) is the cls row
    __syncthreads();
    float* comb = (float*)&P[0][0];   // [4][65] f32 overlay (fits in P[0])
    if (q4 == 0) {
#pragma unroll
      for (int nt = 0; nt < 4; nt++) comb[wave * 65 + nt * 16 + fr] = O1[nt][0];
      if (fr == 0) comb[wave * 65 + 64] = l1[0];
    }
    __syncthreads();
    if (threadIdx.x < 64) {
      int d = threadIdx.x;
      float num = comb[d] + comb[65 + d] + comb[130 + d] + comb[195 + d];
      float den = comb[64] + comb[129] + comb[194] + comb[259];
      ob[((size_t)e * MP + (size_t)b * S_) * DIM_ + hh * DH_ + d] = (bf16_t)(num / den);
    }
    return;
  }

  // per-lane staging sources (two 1024B windows per buffer half)
  int pp0 = wave * 64 + lane, pp1 = 256 + wave * 64 + lane;
  int row0 = pp0 >> 3, ch0 = (pp0 & 7) ^ (row0 & 7);
  int row1 = pp1 >> 3, ch1 = (pp1 & 7) ^ (row1 & 7);
  const bf16_t* gk0 = K + (size_t)row0 * DIM_ + ch0 * 8;
  const bf16_t* gk1 = K + (size_t)row1 * DIM_ + ch1 * 8;
  const bf16_t* gv0 = V + (size_t)row0 * SPK + ch0 * 8;
  const bf16_t* gv1 = V + (size_t)row1 * SPK + ch1 * 8;

#define STAGE_KV(BUF, KS)                                                \
  do {                                                                   \
    async16(gk0 + (size_t)(KS) * DIM_, &Ks[BUF][(wave * 64) * 8]);       \
    async16(gk1 + (size_t)(KS) * DIM_, &Ks[BUF][(256 + wave * 64) * 8]); \
    async16(gv0 + (KS), &Vs[BUF][(wave * 64) * 8]);                      \
    async16(gv1 + (KS), &Vs[BUF][(256 + wave * 64) * 8]);                \
  } while (0)

#define COMP_ATTN(BUF, KS, MASKED)                                            \
  do {                                                                        \
    const bf16_t* Kb = &Ks[BUF][0];                                           \
    const bf16_t* Vb = &Vs[BUF][0];                                           \
    f32x4v sc[2][4] = {};                                                     \
    _Pragma("unroll")                                                         \
    for (int nt = 0; nt < 4; nt++) {                                          \
      int rbase = (nt * 16 + fr) * 8;                                         \
      bf16x8v kf0 = *(const bf16x8v*)&Kb[(rbase + ((q4 + 0) ^ sw)) * 8];      \
      bf16x8v kf1 = *(const bf16x8v*)&Kb[(rbase + ((q4 + 4) ^ sw)) * 8];      \
      _Pragma("unroll")                                                       \
      for (int mt = 0; mt < 2; mt++) {                                        \
        sc[mt][nt] = MFMA(kf0, qf[mt][0], sc[mt][nt]);                        \
        sc[mt][nt] = MFMA(kf1, qf[mt][1], sc[mt][nt]);                        \
      }                                                                       \
    }                                                                         \
    if (MASKED) {                                                             \
      _Pragma("unroll")                                                       \
      for (int nt = 0; nt < 4; nt++)                                          \
        _Pragma("unroll")                                                     \
        for (int c = 0; c < 4; c++)                                           \
          if ((KS) + nt * 16 + q4 * 4 + c >= S_) {                            \
            _Pragma("unroll")                                                 \
            for (int mt = 0; mt < 2; mt++) sc[mt][nt][c] = -1e30f;            \
          }                                                                   \
    }                                                                         \
    _Pragma("unroll")                                                         \
    for (int mt = 0; mt < 2; mt++)                                            \
      _Pragma("unroll")                                                       \
      for (int nt = 0; nt < 4; nt++) {                                        \
        bf16x4v pk;                                                           \
        _Pragma("unroll")                                                     \
        for (int c = 0; c < 4; c++)                                           \
          pk[c] = (bf16_t)__builtin_amdgcn_exp2f(sc[mt][nt][c]);              \
        *(bf16x4v*)&Pw[(mt * 16 + fr) * 72 + nt * 16 + q4 * 4] = pk;          \
      }                                                                       \
    _Pragma("unroll")                                                         \
    for (int kk = 0; kk < 2; kk++) {                                          \
      bf16x8v pa[2];                                                          \
      _Pragma("unroll")                                                       \
      for (int mt = 0; mt < 2; mt++) {                                        \
        pa[mt] = *(const bf16x8v*)&Pw[(mt * 16 + fr) * 72 + q4 * 8 + kk * 32];\
        lacc[mt] = MFMA(pa[mt], ones, lacc[mt]);                              \
      }                                                                       \
      _Pragma("unroll")                                                       \
      for (int nt = 0; nt < 4; nt++) {                                        \
        bf16x8v vf = *(const bf16x8v*)&Vb[((nt * 16 + fr) * 8 +               \
                                           ((q4 + kk * 4) ^ sw)) * 8];        \
        _Pragma("unroll")                                                     \
        for (int mt = 0; mt < 2; mt++)                                        \
          O[mt][nt] = MFMA(pa[mt], vf, O[mt][nt]);                            \
      }                                                                       \
    }                                                                         \
  } while (0)

  bf16x8v qf[2][2];
#pragma unroll
  for (int mt = 0; mt < 2; mt++)
#pragma unroll
    for (int kk = 0; kk < 2; kk++)
      qf[mt][kk] = *(const bf16x8v*)&Q[(size_t)(1 + qt * 128 + wave * 32 + mt * 16 + fr) * DIM_
                                       + q4 * 8 + kk * 32];

  f32x4v O[2][4] = {};
  f32x4v lacc[2] = {};

  // tiles 0..16; loop handles 0..15 (2x-unrolled, static buffers, no mask),
  // tile 16 (the only masked one) is peeled below.
  STAGE_KV(0, 0);
  for (int kt = 0; kt < 16; kt += 2) {
    int ks = kt * 64;
    __syncthreads();               // buf0(t_kt) staged; prior buf1 reads done
    STAGE_KV(1, ks + 64);          // t_{kt+1}, in flight under compute
    COMP_ATTN(0, ks, false);
    __syncthreads();               // buf1 staged; buf0 reads done
    STAGE_KV(0, ks + 128);         // t_{kt+2}; at kt=14 this stages tile 16
    COMP_ATTN(1, ks + 64, false);
  }
  __syncthreads();
  COMP_ATTN(0, 1024, true);        // tile 16, masked

#undef STAGE_KV
#undef COMP_ATTN

#pragma unroll
  for (int mt = 0; mt < 2; mt++)
#pragma unroll
    for (int c = 0; c < 4; c++) {
      int s = 1 + qt * 128 + wave * 32 + mt * 16 + q4 * 4 + c;  // always valid
      float inv = 1.f / lacc[mt][c];
#pragma unroll
      for (int nt = 0; nt < 4; nt++)
        ob[((size_t)e * MP + (size_t)b * S_ + s) * DIM_ + hh * DH_ + nt * 16 + fr]
            = (bf16_t)(O[mt][nt][c] * inv);
    }
}

// ------------------------------------------- GEMM + residual-add (Wo and W2)
__global__ __launch_bounds__(256) void k_gemm_res(
    const bf16_t* __restrict__ abuf, const bf16_t* __restrict__ wt,
    const float* __restrict__ bias, int l, float* __restrict__ t) {
  __shared__ bf16_t As[128 * 32], Bs[128 * 32];
  int e = blockIdx.z;
  const bf16_t* A  = abuf + ((size_t)e * MP + blockIdx.x * 128) * DIM_;
  const bf16_t* Bm = wt + ((size_t)(e * DEPTH_ + l) * DIM_ + blockIdx.y * 128) * DIM_;
  const float* bp = bias + (size_t)(e * DEPTH_ + l) * DIM_;
  f32x4v acc[4][4] = {};
  gemm_core<true>(A, Bm, DIM_, As, Bs, acc);
  EPI2_SETUP();
#pragma unroll
  for (int mt = 0; mt < 4; mt++) {
    int row = rb + mt * 16 + fr;
    if (row < MROWS) {
      float* trow = t + ((size_t)e * MROWS + row) * DIM_;
#pragma unroll
      for (int nt = 0; nt < 4; nt++) {
        int col = cb + nt * 16 + q4 * 4;
        f32x4v o = *(const f32x4v*)&trow[col];
#pragma unroll
        for (int r = 0; r < 4; r++) o[r] += acc[mt][nt][r] + bp[col + r];
        *(f32x4v*)&trow[col] = o;
      }
    }
  }
}

// ----------------------------------------------------------- W1 GEMM + gelu
__global__ __launch_bounds__(256) void k_gemm_gelu(
    const bf16_t* __restrict__ abuf, const bf16_t* __restrict__ wt,
    const float* __restrict__ bias, int l, bf16_t* __restrict__ ub) {
  __shared__ bf16_t As[128 * 32], Bs[128 * 32];
  int e = blockIdx.z;
  const bf16_t* A  = abuf + ((size_t)e * MP + blockIdx.x * 128) * DIM_;
  const bf16_t* Bm = wt + ((size_t)(e * DEPTH_ + l) * DIM_ + blockIdx.y * 128) * DIM_;
  const float* bp = bias + (size_t)(e * DEPTH_ + l) * DIM_;
  f32x4v acc[4][4] = {};
  gemm_core<true>(A, Bm, DIM_, As, Bs, acc);
  EPI2_SETUP();
#pragma unroll
  for (int mt = 0; mt < 4; mt++) {
    int row = rb + mt * 16 + fr;
    if (row < MROWS) {
      bf16_t* urow = ub + ((size_t)e * MP + row) * DIM_;
#pragma unroll
      for (int nt = 0; nt < 4; nt++) {
        int col = cb + nt * 16 + q4 * 4;
        bf16x4v o;
#pragma unroll
        for (int r = 0; r < 4; r++) {
          float v = acc[mt][nt][r] + bp[col + r];
          // jax.nn.gelu tanh form; tanh(u) = 1 - 2/(exp(2u)+1) via fast exp
          float u2 = __expf(1.5957691216057308f * (v + 0.044715f * v * v * v));
          float th = 1.f - 2.f / (u2 + 1.f);
          o[r] = (bf16_t)(0.5f * v * (1.f + th));
        }
        __builtin_nontemporal_store(o, (bf16x4v*)&urow[col]);
      }
    }
  }
}

// ---------------------------------------------------------- head + mixtures
__global__ __launch_bounds__(256) void k_head(const float* __restrict__ lat,
                                              const float* __restrict__ Wh,
                                              const float* __restrict__ bh,
                                              const float* __restrict__ gws,
                                              float* __restrict__ out) {
  int b = blockIdx.x, tid = threadIdx.x;
  for (int d = tid; d < DIM_; d += 256) {
    float a = 0.f;
#pragma unroll
    for (int e = 0; e < 4; e++)
      a += gws[b * 4 + e] * lat[(size_t)(e * B_ + b) * DIM_ + d];
    out[b * DIM_ + d] = a;
  }
  __shared__ float lg[4][10];
  if (tid < 40) {
    int e = tid / 10, c = tid % 10;
    const float* le = lat + (size_t)(e * B_ + b) * DIM_;
    const float* w  = Wh + (size_t)e * DIM_ * C_;
    float a = 0.f;
    for (int d = 0; d < DIM_; d++) a += le[d] * w[d * C_ + c];
    lg[e][c] = a + bh[e * C_ + c];
  }
  __syncthreads();
  if (tid < 10) {
    float a = 0.f;
#pragma unroll
    for (int e = 0; e < 4; e++) a += gws[b * 4 + e] * lg[e][tid];
    out[B_ * DIM_ + b * C_ + tid] = a;
  }
}

// ------------------------------------------------------------------- launch
extern "C" void kernel_launch(void* const* d_in, const int* in_sizes, int n_in,
                              void* d_out, int out_size, void* d_ws, size_t ws_size,
                              hipStream_t stream) {
  const float* x    = (const float*)d_in[0];
  const float* Wr   = (const float*)d_in[1];
  const float* br   = (const float*)d_in[2];
  const float* Wrf  = (const float*)d_in[3];
  const float* brf  = (const float*)d_in[4];
  const float* Wp   = (const float*)d_in[5];
  const float* bp   = (const float*)d_in[6];
  const float* cls  = (const float*)d_in[7];
  const float* ln1g = (const float*)d_in[8];
  const float* ln1b = (const float*)d_in[9];
  const float* Wqkv = (const float*)d_in[10];
  const float* bqkv = (const float*)d_in[11];
  const float* Wo   = (const float*)d_in[12];
  const float* bo   = (const float*)d_in[13];
  const float* ln2g = (const float*)d_in[14];
  const float* ln2b = (const float*)d_in[15];
  const float* W1   = (const float*)d_in[16];
  const float* b1   = (const float*)d_in[17];
  const float* W2   = (const float*)d_in[18];
  const float* b2   = (const float*)d_in[19];
  const float* lnfg = (const float*)d_in[20];
  const float* lnfb = (const float*)d_in[21];
  const float* Wh   = (const float*)d_in[22];
  const float* bh   = (const float*)d_in[23];
  float* out = (float*)d_out;

  // ---- workspace layout (persistent ~154 MiB + union; stream-ordered) ----
  char* w = (char*)d_ws;
  size_t off = 0;
  auto take = [&](size_t bytes) {
    void* p = w + off;
    off += (bytes + 255) & ~(size_t)255;
    return p;
  };
  // persistent region
  bf16_t* wqkv_t = (bf16_t*)take((size_t)E_ * DEPTH_ * 3 * DIM_ * DIM_ * 2);
  bf16_t* wo_t   = (bf16_t*)take((size_t)E_ * DEPTH_ * DIM_ * DIM_ * 2);
  bf16_t* w1_t   = (bf16_t*)take((size_t)E_ * DEPTH_ * DIM_ * DIM_ * 2);
  bf16_t* w2_t   = (bf16_t*)take((size_t)E_ * DEPTH_ * DIM_ * DIM_ * 2);
  float*  tbuf   = (float*)take((size_t)E_ * MROWS * DIM_ * 4);
  bf16_t* hbuf   = (bf16_t*)take((size_t)E_ * MP * DIM_ * 2);
  bf16_t* obuf   = (bf16_t*)take((size_t)E_ * MP * DIM_ * 2);  // q / attn out / W1 out
  float*  racc   = (float*)take((size_t)B_ * DIM_ * 4);
  float*  gws    = (float*)take((size_t)B_ * E_ * 4);
  float*  late   = (float*)take((size_t)E_ * B_ * DIM_ * 4);
  // union region:
  //   view A (dead after k_gemm_proj): x_bf / wr_t / wp_t
  //   view B (rewritten every (l,group)): zc-expert k (row-major) + v
  char* uni = (char*)w + off;
  bf16_t* x_bf = (bf16_t*)(uni);
  bf16_t* wr_t = (bf16_t*)(uni + (size_t)8192 * IN_ * 2);
  bf16_t* wp_t = (bf16_t*)(uni + (size_t)8192 * IN_ * 2 + (size_t)DIM_ * IN_ * 2);
  // pick expert-group width: all 4 experts if workspace allows, else pairs
  size_t kslice_b = (size_t)MP * DIM_ * 2;   // bytes per expert k (row-major)
  size_t vslice_b = KV_SLICE * 2;            // bytes per expert v
  size_t need_full = off + 4 * (kslice_b + vslice_b);
  int zc = (ws_size >= need_full) ? 4 : 2;
  bf16_t* kbuf = (bf16_t*)(uni);
  bf16_t* vbuf = (bf16_t*)(uni + (size_t)zc * kslice_b);
  (void)in_sizes; (void)n_in; (void)out_size;

  // input + weight conversion (weights transposed to [N][K] bf16)
  int n4 = 8192 * IN_ / 4;
  k_cvt<<<(n4 + 255) / 256, 256, 0, stream>>>(x, x_bf, n4);
  dim3 tb(32, 8);
  k_tcvt<<<dim3(DIM_ / 32, IN_ / 32, 1), tb, 0, stream>>>(Wr, wr_t, IN_, DIM_);
  k_tcvt<<<dim3(DIM_ / 32, IN_ / 32, E_), tb, 0, stream>>>(Wp, wp_t, IN_, DIM_);
  k_tcvt<<<dim3(3 * DIM_ / 32, DIM_ / 32, E_ * DEPTH_), tb, 0, stream>>>(Wqkv, wqkv_t, DIM_, 3 * DIM_);
  k_tcvt<<<dim3(DIM_ / 32, DIM_ / 32, E_ * DEPTH_), tb, 0, stream>>>(Wo, wo_t, DIM_, DIM_);
  k_tcvt<<<dim3(DIM_ / 32, DIM_ / 32, E_ * DEPTH_), tb, 0, stream>>>(W1, w1_t, DIM_, DIM_);
  k_tcvt<<<dim3(DIM_ / 32, DIM_ / 32, E_ * DEPTH_), tb, 0, stream>>>(W2, w2_t, DIM_, DIM_);

  // router + expert input projections (z=0 router-pool, z=1..4 experts)
  hipMemsetAsync(racc, 0, (size_t)B_ * DIM_ * 4, stream);
  k_gemm_proj<<<dim3(64, 4, 5), 256, 0, stream>>>(x_bf, wr_t, wp_t, br, bp, racc, tbuf);
  k_cls<<<32, 512, 0, stream>>>(cls, tbuf);
  k_router<<<1, 64, 0, stream>>>(racc, Wrf, brf, gws, out + B_ * DIM_ + B_ * C_);
  // zero v buffer once: its padded s-range [S_, SPK) is never written by the
  // v-GEMM but IS multiplied (by P=0) in attention -- must be finite.
  hipMemsetAsync(vbuf, 0, (size_t)zc * vslice_b, stream);

  for (int l = 0; l < DEPTH_; l++) {
    k_ln<<<MROWS * E_ / 4, 256, 0, stream>>>(tbuf, ln1g, ln1b, l, hbuf);
    for (int eb = 0; eb < E_; eb += zc) {
      k_gemm_qkv<<<dim3(65, 12, zc), 256, 0, stream>>>(hbuf, wqkv_t, bqkv, eb, l,
                                                       obuf, kbuf, vbuf);
      k_attn<<<dim3(576 * zc, 1, 1), 256, 0, stream>>>(obuf, kbuf, vbuf, eb);
    }
    k_gemm_res<<<dim3(65, 4, E_), 256, 0, stream>>>(obuf, wo_t, bo, l, tbuf);
    k_ln<<<MROWS * E_ / 4, 256, 0, stream>>>(tbuf, ln2g, ln2b, l, hbuf);
    k_gemm_gelu<<<dim3(65, 4, E_), 256, 0, stream>>>(hbuf, w1_t, b1, l, obuf);
    k_gemm_res<<<dim3(65, 4, E_), 256, 0, stream>>>(obuf, w2_t, b2, l, tbuf);
  }
  k_lnf<<<32, 256, 0, stream>>>(tbuf, lnfg, lnfb, late);
  k_head<<<8, 256, 0, stream>>>(late, Wh, bh, gws, out);
}

// Round 11
// 941.698 us; speedup vs baseline: 2.9516x; 1.2140x over previous
//
#include <hip/hip_runtime.h>
#include <hip/hip_bf16.h>
#include <math.h>

typedef __bf16 bf16_t;
typedef __bf16 bf16x4v __attribute__((ext_vector_type(4)));
typedef __bf16 bf16x8v __attribute__((ext_vector_type(8)));
typedef float  f32x4v  __attribute__((ext_vector_type(4)));

#define MFMA(a,b,c) __builtin_amdgcn_mfma_f32_16x16x32_bf16(a,b,c,0,0,0)

constexpr int B_ = 8, N_ = 1024, IN_ = 2048, DIM_ = 512, H_ = 8, DH_ = 64;
constexpr int DEPTH_ = 2, E_ = 4, C_ = 10, S_ = 1025;
constexpr int SPK = 1088;       // padded key/value seq len (17*64)
constexpr int MP = 8320;        // padded row count for activations (65*128)
constexpr int MROWS = B_ * S_;  // 8200 valid rows per expert
constexpr size_t KV_SLICE = (size_t)B_ * H_ * SPK * DH_;  // one expert's v
// DH^-0.5 * log2(e): folded into Q at the qkv epilogue (R6: kills 32 v_mul
// per thread per K-tile in attention; softmax math unchanged up to rounding)
#define CL2E 0.18033688011111772f

// Last-layer dead-row elimination (R10): after the final attention, every op
// is ROW-WISE and only the 32 cls rows (b*S_ per e,b) feed the outputs.
// cls row b*1025 lies in 128-row panel 8b  ->  restricted launches keep only
// x-blocks with x%8==0 && x<64.  Conditions are block-uniform (early return
// before any barrier).  Unconsumed rows hold finite garbage (bounded stale
// activations) -- never read downstream.
__device__ __forceinline__ bool skip_panel(int xb) {
  return ((xb & 7) != 0) || (xb >= 64);
}

// ---------------------------------------------------------------- async copy
__device__ __forceinline__ void async16(const void* g, void* l) {
  __builtin_amdgcn_global_load_lds((const __attribute__((address_space(1))) void*)g,
                                   (__attribute__((address_space(3))) void*)l, 16, 0, 0);
}

// ------------------------------------------------------- shared GEMM mainloop
// C[128x128] tile = A[128xK] * B^T[128xK]^T.  Both operands stored [rows][K]
// (weights pre-transposed). 4 waves in 2x2; each wave 64x64 via 4x4 MFMAs.
// SINGLE-buffer, 2-barrier schedule (R5: explicit LDS dbuf is a net LOSS --
// occupancy + L2 churn; implicit overlap across co-resident blocks hides the
// staging latency; matches learn_hip m99/m100/m132).
// R8: never cap VGPR below the accumulator footprint (launch_bounds(256,6)
// spilled acc -> 1.4 GB scratch).  R9: nontemporal stores REFUTED -- FETCH
// unchanged (the +17MB vs R0 is reads, not write-RFO) and WRITE +25MB
// (NT partial lines bypass L2 coalescing).  Plain stores.
// LDS chunk-rotation swizzle: slot s of row R holds global 16B chunk
// (s - (R>>1)) & 3 -> conflict-free reads (SQ_LDS_BANK_CONFLICT = 0).
// SW=true (default): operands SWAPPED -- MFMA(bfr, af) -- so the C-frag is
// TRANSPOSED: acc[mt][nt][r]: row = RB + mt*16 + fr, col = CB + nt*16 + q4*4
// + r.  Each lane's 4 regs = 4 consecutive COLUMNS -> epilogues pack vec4
// stores.  SW=false: legacy orientation (row = RB + mt*16 + q4*4 + r,
// col = CB + nt*16 + fr) used by the V gemm.
template <bool SW>
__device__ __forceinline__ void gemm_core(const bf16_t* __restrict__ A,
                                          const bf16_t* __restrict__ Bm, int K,
                                          bf16_t* As, bf16_t* Bs,
                                          f32x4v acc[4][4]) {
  const int tid  = threadIdx.x;
  const int lane = tid & 63, wave = tid >> 6;
  const int fr = lane & 15, q4 = lane >> 4;
  const int wm = (wave >> 1) * 64, wn = (wave & 1) * 64;
  // staging: wave w fills rows [w*32, w*32+32) of both tiles
  const int srow = wave * 32 + (lane >> 2);
  const int scol = (((lane & 3) - (lane >> 3)) & 3) * 8;   // swizzled chunk
  const int sl   = ((q4 + (fr >> 1)) & 3) * 8;             // read-side slot
  const bf16_t* ga = A  + (size_t)srow * K + scol;
  const bf16_t* gb = Bm + (size_t)srow * K + scol;
  bf16_t* la = As + wave * 1024;  // wave-uniform LDS base; HW adds lane*16B
  bf16_t* lb = Bs + wave * 1024;
  for (int k0 = 0; k0 < K; k0 += 32) {
    async16(ga + k0,          la);
    async16(ga + k0 + 16 * K, la + 512);
    async16(gb + k0,          lb);
    async16(gb + k0 + 16 * K, lb + 512);
    __syncthreads();   // drains vmcnt(0): staged data visible
    bf16x8v af[4], bfr[4];
#pragma unroll
    for (int mt = 0; mt < 4; mt++)
      af[mt] = *(const bf16x8v*)&As[(wm + mt * 16 + fr) * 32 + sl];
#pragma unroll
    for (int nt = 0; nt < 4; nt++)
      bfr[nt] = *(const bf16x8v*)&Bs[(wn + nt * 16 + fr) * 32 + sl];
#pragma unroll
    for (int mt = 0; mt < 4; mt++)
#pragma unroll
      for (int nt = 0; nt < 4; nt++)
        acc[mt][nt] = SW ? MFMA(bfr[nt], af[mt], acc[mt][nt])
                         : MFMA(af[mt], bfr[nt], acc[mt][nt]);
    __syncthreads();   // all reads done before next stage overwrites
  }
}

// swapped-frag epilogue index helper:
// acc[mt][nt][r]: row = rb + mt*16 + fr, col = cb + nt*16 + q4*4 + r
#define EPI2_SETUP()                                                   \
  int lane = threadIdx.x & 63, wave = threadIdx.x >> 6;                \
  int fr = lane & 15, q4 = lane >> 4;                                  \
  int rb = blockIdx.x * 128 + (wave >> 1) * 64;                        \
  int cb = blockIdx.y * 128 + (wave & 1) * 64;

// ----------------------------------------------------------------- converts
__global__ __launch_bounds__(256) void k_cvt(const float* __restrict__ in,
                                             bf16_t* __restrict__ out, int n4) {
  int i = blockIdx.x * blockDim.x + threadIdx.x;
  if (i < n4) {
    float4 v = ((const float4*)in)[i];
    bf16x4v o = {(bf16_t)v.x, (bf16_t)v.y, (bf16_t)v.z, (bf16_t)v.w};
    ((bf16x4v*)out)[i] = o;
  }
}

// in [nmat][K][N] f32 -> out [nmat][N][K] bf16 (K,N multiples of 32)
__global__ __launch_bounds__(256) void k_tcvt(const float* __restrict__ in,
                                              bf16_t* __restrict__ out, int K, int N) {
  __shared__ float tile[32][33];
  size_t mb = (size_t)blockIdx.z * K * N;
  int k0 = blockIdx.y * 32, n0 = blockIdx.x * 32;
  int tx = threadIdx.x, ty = threadIdx.y;
#pragma unroll
  for (int i = 0; i < 32; i += 8)
    tile[ty + i][tx] = in[mb + (size_t)(k0 + ty + i) * N + n0 + tx];
  __syncthreads();
#pragma unroll
  for (int i = 0; i < 32; i += 8)
    out[mb + (size_t)(n0 + ty + i) * K + k0 + tx] = (bf16_t)tile[tx][ty + i];
}

// ------------------------------------------------- proj GEMM (router+experts)
// z=0: router relu -> atomic mean-pool partials into racc[B][DIM]
// z=1..4: expert relu -> t[e][b][1+n][d] (vec4 f32 stores)
__global__ __launch_bounds__(256) void k_gemm_proj(
    const bf16_t* __restrict__ xbf, const bf16_t* __restrict__ wrt,
    const bf16_t* __restrict__ wpt, const float* __restrict__ br,
    const float* __restrict__ bp, float* __restrict__ racc,
    float* __restrict__ t) {
  __shared__ bf16_t As[128 * 32], Bs[128 * 32];
  int z = blockIdx.z;
  const bf16_t* A  = xbf + (size_t)blockIdx.x * 128 * IN_;
  const bf16_t* Bm = (z == 0 ? wrt : wpt + (size_t)(z - 1) * DIM_ * IN_)
                     + (size_t)blockIdx.y * 128 * IN_;
  const float* bias = (z == 0) ? br : bp + (z - 1) * DIM_;
  f32x4v acc[4][4] = {};
  gemm_core<true>(A, Bm, IN_, As, Bs, acc);
  EPI2_SETUP();
  if (z == 0) {
    // all 128 rows of this block belong to batch b = blockIdx.x>>3;
    // reduce relu'd values over the wave's 64 rows (mt x fr), then one
    // atomic per column from the fr==0 lanes.
    int b = blockIdx.x >> 3;
#pragma unroll
    for (int nt = 0; nt < 4; nt++)
#pragma unroll
      for (int r = 0; r < 4; r++) {
        int col = cb + nt * 16 + q4 * 4 + r;
        float p = 0.f;
#pragma unroll
        for (int mt = 0; mt < 4; mt++)
          p += fmaxf(acc[mt][nt][r] + bias[col], 0.f);
#pragma unroll
        for (int o = 1; o < 16; o <<= 1) p += __shfl_xor(p, o, 64);
        if (fr == 0) atomicAdd(&racc[b * DIM_ + col], p);
      }
  } else {
    int e = z - 1;
#pragma unroll
    for (int mt = 0; mt < 4; mt++) {
      int row = rb + mt * 16 + fr;          // always < 8192 (grid.x = 64)
      int b = row >> 10, n = row & 1023;
      float* trow = t + ((size_t)(e * B_ + b) * S_ + 1 + n) * DIM_;
#pragma unroll
      for (int nt = 0; nt < 4; nt++) {
        int col = cb + nt * 16 + q4 * 4;
        f32x4v o;
#pragma unroll
        for (int r = 0; r < 4; r++)
          o[r] = fmaxf(acc[mt][nt][r] + bias[col + r], 0.f);
        *(f32x4v*)&trow[col] = o;
      }
    }
  }
}

__global__ __launch_bounds__(512) void k_cls(const float* __restrict__ cls,
                                             float* __restrict__ t) {
  // block = (e*8+b); s=0 row
  t[(size_t)blockIdx.x * S_ * DIM_ + threadIdx.x] =
      cls[(blockIdx.x >> 3) * DIM_ + threadIdx.x];
}

// ------------------------------------------------------------------ router
__global__ __launch_bounds__(64) void k_router(const float* __restrict__ racc,
                                               const float* __restrict__ Wrf,
                                               const float* __restrict__ brf,
                                               float* __restrict__ gws,
                                               float* __restrict__ outg) {
  __shared__ float lg[8][4];
  int t = threadIdx.x;
  if (t < 32) {
    int b = t >> 2, e = t & 3;
    const float* r = racc + b * DIM_;
    float a = 0.f;
    for (int d = 0; d < DIM_; d++) a += r[d] * Wrf[d * 4 + e];
    lg[b][e] = a * (1.f / N_) + brf[e];
  }
  __syncthreads();
  if (t < 8) {
    int b = t;
    float mx = fmaxf(fmaxf(lg[b][0], lg[b][1]), fmaxf(lg[b][2], lg[b][3]));
    float s = 0.f, g[4];
#pragma unroll
    for (int e = 0; e < 4; e++) { g[e] = __expf(lg[b][e] - mx); s += g[e]; }
#pragma unroll
    for (int e = 0; e < 4; e++) {
      float gv = g[e] / s;
      gws[b * 4 + e] = gv;
      outg[b * 4 + e] = gv;
    }
  }
}

// ------------- layernorm: one wave per row, 4 rows/block (vectorized f32x4)
__global__ __launch_bounds__(256) void k_ln(const float* __restrict__ t,
                                            const float* __restrict__ gg,
                                            const float* __restrict__ bb, int l,
                                            bf16_t* __restrict__ h) {
  int r = blockIdx.x * 4 + (threadIdx.x >> 6);   // global row in [0, E*B*S)
  int lane = threadIdx.x & 63;
  int e = r / MROWS;
  const f32x4v* row = (const f32x4v*)(t + (size_t)r * DIM_);
  f32x4v v0 = row[lane], v1 = row[lane + 64];
  float sum = 0.f, sq = 0.f;
#pragma unroll
  for (int j = 0; j < 4; j++) {
    sum += v0[j] + v1[j];
    sq  += v0[j] * v0[j] + v1[j] * v1[j];
  }
#pragma unroll
  for (int o = 1; o < 64; o <<= 1) {
    sum += __shfl_xor(sum, o, 64);
    sq  += __shfl_xor(sq, o, 64);
  }
  float mean = sum * (1.f / DIM_);
  float var  = sq * (1.f / DIM_) - mean * mean;
  float rstd = rsqrtf(var + 1e-5f);
  const f32x4v* gp = (const f32x4v*)(gg + (size_t)(e * DEPTH_ + l) * DIM_);
  const f32x4v* bp = (const f32x4v*)(bb + (size_t)(e * DEPTH_ + l) * DIM_);
  f32x4v g0 = gp[lane], g1 = gp[lane + 64];
  f32x4v b0 = bp[lane], b1 = bp[lane + 64];
  bf16_t* orow = h + ((size_t)r + (size_t)e * (MP - MROWS)) * DIM_;
  bf16x4v o0, o1;
#pragma unroll
  for (int j = 0; j < 4; j++) {
    o0[j] = (bf16_t)((v0[j] - mean) * rstd * g0[j] + b0[j]);
    o1[j] = (bf16_t)((v1[j] - mean) * rstd * g1[j] + b1[j]);
  }
  ((bf16x4v*)orow)[lane]      = o0;
  ((bf16x4v*)orow)[lane + 64] = o1;
}

__global__ __launch_bounds__(256) void k_lnf(const float* __restrict__ t,
                                             const float* __restrict__ gg,
                                             const float* __restrict__ bb,
                                             float* __restrict__ lat) {
  int eb = blockIdx.x, e = eb >> 3;
  const float* row = t + (size_t)eb * S_ * DIM_;  // s=0 (cls)
  int tid = threadIdx.x;
  float v0 = row[tid], v1 = row[tid + 256];
  float sum = v0 + v1, sq = v0 * v0 + v1 * v1;
  for (int o = 32; o > 0; o >>= 1) {
    sum += __shfl_down(sum, o, 64);
    sq  += __shfl_down(sq, o, 64);
  }
  __shared__ float sb[8];
  int lane = tid & 63, wave = tid >> 6;
  if (lane == 0) { sb[wave * 2] = sum; sb[wave * 2 + 1] = sq; }
  __syncthreads();
  float ts = sb[0] + sb[2] + sb[4] + sb[6];
  float tq = sb[1] + sb[3] + sb[5] + sb[7];
  float mean = ts * (1.f / DIM_);
  float var  = tq * (1.f / DIM_) - mean * mean;
  float rstd = rsqrtf(var + 1e-5f);
  lat[(size_t)eb * DIM_ + tid]       = (v0 - mean) * rstd * gg[e * DIM_ + tid] + bb[e * DIM_ + tid];
  lat[(size_t)eb * DIM_ + tid + 256] = (v1 - mean) * rstd * gg[e * DIM_ + tid + 256] + bb[e * DIM_ + tid + 256];
}

// -------------------- fused QKV GEMM (zc experts per launch)
// y in [0,4):  q -- swapped frag, vec4 row-major store into qo[e][MP][DIM],
//              PRE-SCALED by CL2E.  When qres (last layer): only the 8
//              cls-bearing panels per expert are computed.
// y in [4,8):  k -- swapped frag, vec4 ROW-MAJOR store into kb[esub][MP][DIM].
// y in [8,12): v -- legacy orientation (A = V-channel weight rows, Bm =
//              activation rows) so the V^T store (vb[dh][s]) is contiguous.
__global__ __launch_bounds__(256) void k_gemm_qkv(
    const bf16_t* __restrict__ h, const bf16_t* __restrict__ wt,
    const float* __restrict__ bias, int ebase, int l, int qres,
    bf16_t* __restrict__ qo, bf16_t* __restrict__ kb, bf16_t* __restrict__ vb) {
  if (qres && blockIdx.y < 4 && skip_panel(blockIdx.x)) return;
  __shared__ bf16_t As[128 * 32], Bs[128 * 32];
  int esub = blockIdx.z, e = ebase + esub;
  const float* bp = bias + (size_t)(e * DEPTH_ + l) * (3 * DIM_);
  f32x4v acc[4][4] = {};
  if (blockIdx.y < 8) {
    const bf16_t* A  = h + ((size_t)e * MP + blockIdx.x * 128) * DIM_;
    const bf16_t* Bm = wt + ((size_t)(e * DEPTH_ + l) * (3 * DIM_) + blockIdx.y * 128) * DIM_;
    gemm_core<true>(A, Bm, DIM_, As, Bs, acc);
    EPI2_SETUP();
    bf16_t* dst;
    int coff;
    float scale;
    if (blockIdx.y < 4) { dst = qo + (size_t)e * MP * DIM_;    coff = 0;   scale = CL2E; }
    else                { dst = kb + (size_t)esub * MP * DIM_; coff = 512; scale = 1.f; }
#pragma unroll
    for (int mt = 0; mt < 4; mt++) {
      int row = rb + mt * 16 + fr;
      if (row < MROWS) {
#pragma unroll
        for (int nt = 0; nt < 4; nt++) {
          int col = cb + nt * 16 + q4 * 4;
          bf16x4v o;
#pragma unroll
          for (int r = 0; r < 4; r++)
            o[r] = (bf16_t)((acc[mt][nt][r] + bp[col + r]) * scale);
          *(bf16x4v*)&dst[(size_t)row * DIM_ + (col - coff)] = o;
        }
      }
    }
  } else {
    size_t slice = (size_t)esub * KV_SLICE;
    int yv = blockIdx.y - 8;
    const bf16_t* A  = wt + ((size_t)(e * DEPTH_ + l) * (3 * DIM_) + 1024 + yv * 128) * DIM_;
    const bf16_t* Bm = h + ((size_t)e * MP + blockIdx.x * 128) * DIM_;
    gemm_core<false>(A, Bm, DIM_, As, Bs, acc);
    // legacy roles: frag row -> V channel, frag col -> token row
    int lane = threadIdx.x & 63, wave = threadIdx.x >> 6;
    int wb = yv * 128 + (wave >> 1) * 64 + ((lane >> 4) << 2);
    int sb = blockIdx.x * 128 + (wave & 1) * 64 + (lane & 15);
#pragma unroll
    for (int mt = 0; mt < 4; mt++)
#pragma unroll
      for (int nt = 0; nt < 4; nt++)
#pragma unroll
        for (int r = 0; r < 4; r++) {
          int srow = sb + nt * 16;
          if (srow < MROWS) {
            int wch = wb + mt * 16 + r;        // 0..511 within V region
            float v = acc[mt][nt][r] + bp[1024 + wch];
            int b = srow / S_, s = srow - b * S_;
            int hh = wch >> 6, dh = wch & 63;
            vb[slice + ((size_t)b * H_ + hh) * DH_ * SPK + (size_t)dh * SPK + s] = (bf16_t)v;
          }
        }
  }
}

// --------------------------------- flash attention (zc experts per launch)
// 1-D grid, XCD-aware decode (T1): HW assigns block i -> XCD i%8; each XCD
// gets whole (z,h) groups of 9 qt-blocks so a group's K/V slice is fetched
// into ONE XCD L2 (R6/R7: FETCH -8x, attn 145 -> <120 us).
// Q is read from ob (row-major [e][MP][DIM], PRE-SCALED by CL2E) and O is
// written IN PLACE.  clsonly (last layer): only the qt==8 cls blocks run --
// downstream consumes nothing but the cls attention rows.
// qt<8: 128 q-rows (tokens 1..1024).  qt==8: cls row via split-K across the
// 4 waves.  K/V staged via global_load_lds, double-buffered; kt-loop is
// 2x-unrolled with STATIC buffer bases; masked tile 16 peeled to epilogue.
// S^T trick: QK^T computed with operands SWAPPED -- MFMA(kf, qf).
// No max-subtraction (|s| <~ 2); rowsum via ones-MFMA.  K rows beyond MROWS
// are garbage but masked by ASSIGNMENT (NaN-safe); V padding is zeroed once.
__global__ __launch_bounds__(256, 3) void k_attn(bf16_t* ob,
                                                 const bf16_t* __restrict__ kb,
                                                 const bf16_t* __restrict__ vb,
                                                 int ebase, int clsonly) {
  __shared__ bf16_t P[4][32 * 72];
  __shared__ bf16_t Ks[2][4096], Vs[2][4096];
  // XCD-aware decode: i%8 = XCD, groups of 9 consecutive j on one XCD
  int zc8 = (int)gridDim.x / 72;         // 8*zc  (grid = 576*zc)
  int xcd = blockIdx.x & 7;
  int j   = blockIdx.x >> 3;
  int grp = xcd * zc8 + j / 9;           // (z,h) group id
  int qt  = j % 9;
  int hh  = grp & 7;
  int z   = grp >> 3;                    // esub*8 + b
  int esub = z >> 3, b = z & 7;
  if (clsonly && qt != 8) return;
  int e = ebase + esub;
  size_t slice = (size_t)esub * KV_SLICE;
  const bf16_t* Q = ob + ((size_t)e * MP + (size_t)b * S_) * DIM_ + hh * DH_;
  const bf16_t* K = kb + ((size_t)esub * MP + (size_t)b * S_) * DIM_ + hh * DH_;
  const bf16_t* V = vb + slice + ((size_t)b * H_ + hh) * DH_ * SPK;
  int lane = threadIdx.x & 63, wave = threadIdx.x >> 6;
  int fr = lane & 15, q4 = lane >> 4;
  int sw = fr & 7;                  // per-lane read-side swizzle
  bf16_t* Pw = &P[wave][0];

  bf16x8v ones;
#pragma unroll
  for (int jj = 0; jj < 8; jj++) ones[jj] = (bf16_t)1.0f;

  if (qt == 8) {
    // ---------------- cls row (s=0): per-wave key-tile subsets, no LDS stage
    bf16x8v qf0[2];
#pragma unroll
    for (int kk = 0; kk < 2; kk++)
      qf0[kk] = *(const bf16x8v*)&Q[q4 * 8 + kk * 32];
    f32x4v O1[4] = {};
    f32x4v l1 = {};
    for (int kt = wave; kt < 17; kt += 4) {
      int ks = kt * 64;
      f32x4v sc[4] = {};
#pragma unroll
      for (int nt = 0; nt < 4; nt++) {
        bf16x8v kf0 = *(const bf16x8v*)&K[(size_t)(ks + nt * 16 + fr) * DIM_ + q4 * 8];
        bf16x8v kf1 = *(const bf16x8v*)&K[(size_t)(ks + nt * 16 + fr) * DIM_ + q4 * 8 + 32];
        sc[nt] = MFMA(kf0, qf0[0], sc[nt]);
        sc[nt] = MFMA(kf1, qf0[1], sc[nt]);
      }
      if (ks + 64 > S_) {
#pragma unroll
        for (int nt = 0; nt < 4; nt++)
#pragma unroll
          for (int c = 0; c < 4; c++)
            if (ks + nt * 16 + q4 * 4 + c >= S_) sc[nt][c] = -1e30f;
      }
#pragma unroll
      for (int nt = 0; nt < 4; nt++) {
        bf16x4v pk;
#pragma unroll
        for (int c = 0; c < 4; c++)
          pk[c] = (bf16_t)__builtin_amdgcn_exp2f(sc[nt][c]);
        *(bf16x4v*)&Pw[fr * 72 + nt * 16 + q4 * 4] = pk;
      }
#pragma unroll
      for (int kk = 0; kk < 2; kk++) {
        bf16x8v pa = *(const bf16x8v*)&Pw[fr * 72 + q4 * 8 + kk * 32];
        l1 = MFMA(pa, ones, l1);
#pragma unroll
        for (int nt = 0; nt < 4; nt++) {
          bf16x8v vf = *(const bf16x8v*)&V[(size_t)(nt * 16 + fr) * SPK + ks + (q4 + kk * 4) * 8];
          O1[nt] = MFMA(pa, vf, O1[nt]);
        }
      }
    }
    // combine waves: only D-row 0 (lanes q4==0, component c==0) is the cls row
    __syncthreads();
    float* comb = (float*)&P[0][0];   // [4][65] f32 overlay (fits in P[0])
    if (q4 == 0) {
#pragma unroll
      for (int nt = 0; nt < 4; nt++) comb[wave * 65 + nt * 16 + fr] = O1[nt][0];
      if (fr == 0) comb[wave * 65 + 64] = l1[0];
    }
    __syncthreads();
    if (threadIdx.x < 64) {
      int d = threadIdx.x;
      float num = comb[d] + comb[65 + d] + comb[130 + d] + comb[195 + d];
      float den = comb[64] + comb[129] + comb[194] + comb[259];
      ob[((size_t)e * MP + (size_t)b * S_) * DIM_ + hh * DH_ + d] = (bf16_t)(num / den);
    }
    return;
  }

  // per-lane staging sources (two 1024B windows per buffer half)
  int pp0 = wave * 64 + lane, pp1 = 256 + wave * 64 + lane;
  int row0 = pp0 >> 3, ch0 = (pp0 & 7) ^ (row0 & 7);
  int row1 = pp1 >> 3, ch1 = (pp1 & 7) ^ (row1 & 7);
  const bf16_t* gk0 = K + (size_t)row0 * DIM_ + ch0 * 8;
  const bf16_t* gk1 = K + (size_t)row1 * DIM_ + ch1 * 8;
  const bf16_t* gv0 = V + (size_t)row0 * SPK + ch0 * 8;
  const bf16_t* gv1 = V + (size_t)row1 * SPK + ch1 * 8;

#define STAGE_KV(BUF, KS)                                                \
  do {                                                                   \
    async16(gk0 + (size_t)(KS) * DIM_, &Ks[BUF][(wave * 64) * 8]);       \
    async16(gk1 + (size_t)(KS) * DIM_, &Ks[BUF][(256 + wave * 64) * 8]); \
    async16(gv0 + (KS), &Vs[BUF][(wave * 64) * 8]);                      \
    async16(gv1 + (KS), &Vs[BUF][(256 + wave * 64) * 8]);                \
  } while (0)

#define COMP_ATTN(BUF, KS, MASKED)                                            \
  do {                                                                        \
    const bf16_t* Kb = &Ks[BUF][0];                                           \
    const bf16_t* Vb = &Vs[BUF][0];                                           \
    f32x4v sc[2][4] = {};                                                     \
    _Pragma("unroll")                                                         \
    for (int nt = 0; nt < 4; nt++) {                                          \
      int rbase = (nt * 16 + fr) * 8;                                         \
      bf16x8v kf0 = *(const bf16x8v*)&Kb[(rbase + ((q4 + 0) ^ sw)) * 8];      \
      bf16x8v kf1 = *(const bf16x8v*)&Kb[(rbase + ((q4 + 4) ^ sw)) * 8];      \
      _Pragma("unroll")                                                       \
      for (int mt = 0; mt < 2; mt++) {                                        \
        sc[mt][nt] = MFMA(kf0, qf[mt][0], sc[mt][nt]);                        \
        sc[mt][nt] = MFMA(kf1, qf[mt][1], sc[mt][nt]);                        \
      }                                                                       \
    }                                                                         \
    if (MASKED) {                                                             \
      _Pragma("unroll")                                                       \
      for (int nt = 0; nt < 4; nt++)                                          \
        _Pragma("unroll")                                                     \
        for (int c = 0; c < 4; c++)                                           \
          if ((KS) + nt * 16 + q4 * 4 + c >= S_) {                            \
            _Pragma("unroll")                                                 \
            for (int mt = 0; mt < 2; mt++) sc[mt][nt][c] = -1e30f;            \
          }                                                                   \
    }                                                                         \
    _Pragma("unroll")                                                         \
    for (int mt = 0; mt < 2; mt++)                                            \
      _Pragma("unroll")                                                       \
      for (int nt = 0; nt < 4; nt++) {                                        \
        bf16x4v pk;                                                           \
        _Pragma("unroll")                                                     \
        for (int c = 0; c < 4; c++)                                           \
          pk[c] = (bf16_t)__builtin_amdgcn_exp2f(sc[mt][nt][c]);              \
        *(bf16x4v*)&Pw[(mt * 16 + fr) * 72 + nt * 16 + q4 * 4] = pk;          \
      }                                                                       \
    _Pragma("unroll")                                                         \
    for (int kk = 0; kk < 2; kk++) {                                          \
      bf16x8v pa[2];                                                          \
      _Pragma("unroll")                                                       \
      for (int mt = 0; mt < 2; mt++) {                                        \
        pa[mt] = *(const bf16x8v*)&Pw[(mt * 16 + fr) * 72 + q4 * 8 + kk * 32];\
        lacc[mt] = MFMA(pa[mt], ones, lacc[mt]);                              \
      }                                                                       \
      _Pragma("unroll")                                                       \
      for (int nt = 0; nt < 4; nt++) {                                        \
        bf16x8v vf = *(const bf16x8v*)&Vb[((nt * 16 + fr) * 8 +               \
                                           ((q4 + kk * 4) ^ sw)) * 8];        \
        _Pragma("unroll")                                                     \
        for (int mt = 0; mt < 2; mt++)                                        \
          O[mt][nt] = MFMA(pa[mt], vf, O[mt][nt]);                            \
      }                                                                       \
    }                                                                         \
  } while (0)

  bf16x8v qf[2][2];
#pragma unroll
  for (int mt = 0; mt < 2; mt++)
#pragma unroll
    for (int kk = 0; kk < 2; kk++)
      qf[mt][kk] = *(const bf16x8v*)&Q[(size_t)(1 + qt * 128 + wave * 32 + mt * 16 + fr) * DIM_
                                       + q4 * 8 + kk * 32];

  f32x4v O[2][4] = {};
  f32x4v lacc[2] = {};

  // tiles 0..16; loop handles 0..15 (2x-unrolled, static buffers, no mask),
  // tile 16 (the only masked one) is peeled below.
  STAGE_KV(0, 0);
  for (int kt = 0; kt < 16; kt += 2) {
    int ks = kt * 64;
    __syncthreads();               // buf0(t_kt) staged; prior buf1 reads done
    STAGE_KV(1, ks + 64);          // t_{kt+1}, in flight under compute
    COMP_ATTN(0, ks, false);
    __syncthreads();               // buf1 staged; buf0 reads done
    STAGE_KV(0, ks + 128);         // t_{kt+2}; at kt=14 this stages tile 16
    COMP_ATTN(1, ks + 64, false);
  }
  __syncthreads();
  COMP_ATTN(0, 1024, true);        // tile 16, masked

#undef STAGE_KV
#undef COMP_ATTN

#pragma unroll
  for (int mt = 0; mt < 2; mt++)
#pragma unroll
    for (int c = 0; c < 4; c++) {
      int s = 1 + qt * 128 + wave * 32 + mt * 16 + q4 * 4 + c;  // always valid
      float inv = 1.f / lacc[mt][c];
#pragma unroll
      for (int nt = 0; nt < 4; nt++)
        ob[((size_t)e * MP + (size_t)b * S_ + s) * DIM_ + hh * DH_ + nt * 16 + fr]
            = (bf16_t)(O[mt][nt][c] * inv);
    }
}

// ------------------------------------------- GEMM + residual-add (Wo and W2)
// rres (last layer): only the 8 cls-bearing panels per expert are computed.
__global__ __launch_bounds__(256) void k_gemm_res(
    const bf16_t* __restrict__ abuf, const bf16_t* __restrict__ wt,
    const float* __restrict__ bias, int l, int rres, float* __restrict__ t) {
  if (rres && skip_panel(blockIdx.x)) return;
  __shared__ bf16_t As[128 * 32], Bs[128 * 32];
  int e = blockIdx.z;
  const bf16_t* A  = abuf + ((size_t)e * MP + blockIdx.x * 128) * DIM_;
  const bf16_t* Bm = wt + ((size_t)(e * DEPTH_ + l) * DIM_ + blockIdx.y * 128) * DIM_;
  const float* bp = bias + (size_t)(e * DEPTH_ + l) * DIM_;
  f32x4v acc[4][4] = {};
  gemm_core<true>(A, Bm, DIM_, As, Bs, acc);
  EPI2_SETUP();
#pragma unroll
  for (int mt = 0; mt < 4; mt++) {
    int row = rb + mt * 16 + fr;
    if (row < MROWS) {
      float* trow = t + ((size_t)e * MROWS + row) * DIM_;
#pragma unroll
      for (int nt = 0; nt < 4; nt++) {
        int col = cb + nt * 16 + q4 * 4;
        f32x4v o = *(const f32x4v*)&trow[col];
#pragma unroll
        for (int r = 0; r < 4; r++) o[r] += acc[mt][nt][r] + bp[col + r];
        *(f32x4v*)&trow[col] = o;
      }
    }
  }
}

// ----------------------------------------------------------- W1 GEMM + gelu
__global__ __launch_bounds__(256) void k_gemm_gelu(
    const bf16_t* __restrict__ abuf, const bf16_t* __restrict__ wt,
    const float* __restrict__ bias, int l, int rres, bf16_t* __restrict__ ub) {
  if (rres && skip_panel(blockIdx.x)) return;
  __shared__ bf16_t As[128 * 32], Bs[128 * 32];
  int e = blockIdx.z;
  const bf16_t* A  = abuf + ((size_t)e * MP + blockIdx.x * 128) * DIM_;
  const bf16_t* Bm = wt + ((size_t)(e * DEPTH_ + l) * DIM_ + blockIdx.y * 128) * DIM_;
  const float* bp = bias + (size_t)(e * DEPTH_ + l) * DIM_;
  f32x4v acc[4][4] = {};
  gemm_core<true>(A, Bm, DIM_, As, Bs, acc);
  EPI2_SETUP();
#pragma unroll
  for (int mt = 0; mt < 4; mt++) {
    int row = rb + mt * 16 + fr;
    if (row < MROWS) {
      bf16_t* urow = ub + ((size_t)e * MP + row) * DIM_;
#pragma unroll
      for (int nt = 0; nt < 4; nt++) {
        int col = cb + nt * 16 + q4 * 4;
        bf16x4v o;
#pragma unroll
        for (int r = 0; r < 4; r++) {
          float v = acc[mt][nt][r] + bp[col + r];
          // jax.nn.gelu tanh form; tanh(u) = 1 - 2/(exp(2u)+1) via fast exp
          float u2 = __expf(1.5957691216057308f * (v + 0.044715f * v * v * v));
          float th = 1.f - 2.f / (u2 + 1.f);
          o[r] = (bf16_t)(0.5f * v * (1.f + th));
        }
        *(bf16x4v*)&urow[col] = o;
      }
    }
  }
}

// ---------------------------------------------------------- head + mixtures
__global__ __launch_bounds__(256) void k_head(const float* __restrict__ lat,
                                              const float* __restrict__ Wh,
                                              const float* __restrict__ bh,
                                              const float* __restrict__ gws,
                                              float* __restrict__ out) {
  int b = blockIdx.x, tid = threadIdx.x;
  for (int d = tid; d < DIM_; d += 256) {
    float a = 0.f;
#pragma unroll
    for (int e = 0; e < 4; e++)
      a += gws[b * 4 + e] * lat[(size_t)(e * B_ + b) * DIM_ + d];
    out[b * DIM_ + d] = a;
  }
  __shared__ float lg[4][10];
  if (tid < 40) {
    int e = tid / 10, c = tid % 10;
    const float* le = lat + (size_t)(e * B_ + b) * DIM_;
    const float* w  = Wh + (size_t)e * DIM_ * C_;
    float a = 0.f;
    for (int d = 0; d < DIM_; d++) a += le[d] * w[d * C_ + c];
    lg[e][c] = a + bh[e * C_ + c];
  }
  __syncthreads();
  if (tid < 10) {
    float a = 0.f;
#pragma unroll
    for (int e = 0; e < 4; e++) a += gws[b * 4 + e] * lg[e][tid];
    out[B_ * DIM_ + b * C_ + tid] = a;
  }
}

// ------------------------------------------------------------------- launch
extern "C" void kernel_launch(void* const* d_in, const int* in_sizes, int n_in,
                              void* d_out, int out_size, void* d_ws, size_t ws_size,
                              hipStream_t stream) {
  const float* x    = (const float*)d_in[0];
  const float* Wr   = (const float*)d_in[1];
  const float* br   = (const float*)d_in[2];
  const float* Wrf  = (const float*)d_in[3];
  const float* brf  = (const float*)d_in[4];
  const float* Wp   = (const float*)d_in[5];
  const float* bp   = (const float*)d_in[6];
  const float* cls  = (const float*)d_in[7];
  const float* ln1g = (const float*)d_in[8];
  const float* ln1b = (const float*)d_in[9];
  const float* Wqkv = (const float*)d_in[10];
  const float* bqkv = (const float*)d_in[11];
  const float* Wo   = (const float*)d_in[12];
  const float* bo   = (const float*)d_in[13];
  const float* ln2g = (const float*)d_in[14];
  const float* ln2b = (const float*)d_in[15];
  const float* W1   = (const float*)d_in[16];
  const float* b1   = (const float*)d_in[17];
  const float* W2   = (const float*)d_in[18];
  const float* b2   = (const float*)d_in[19];
  const float* lnfg = (const float*)d_in[20];
  const float* lnfb = (const float*)d_in[21];
  const float* Wh   = (const float*)d_in[22];
  const float* bh   = (const float*)d_in[23];
  float* out = (float*)d_out;

  // ---- workspace layout (persistent ~154 MiB + union; stream-ordered) ----
  char* w = (char*)d_ws;
  size_t off = 0;
  auto take = [&](size_t bytes) {
    void* p = w + off;
    off += (bytes + 255) & ~(size_t)255;
    return p;
  };
  // persistent region
  bf16_t* wqkv_t = (bf16_t*)take((size_t)E_ * DEPTH_ * 3 * DIM_ * DIM_ * 2);
  bf16_t* wo_t   = (bf16_t*)take((size_t)E_ * DEPTH_ * DIM_ * DIM_ * 2);
  bf16_t* w1_t   = (bf16_t*)take((size_t)E_ * DEPTH_ * DIM_ * DIM_ * 2);
  bf16_t* w2_t   = (bf16_t*)take((size_t)E_ * DEPTH_ * DIM_ * DIM_ * 2);
  float*  tbuf   = (float*)take((size_t)E_ * MROWS * DIM_ * 4);
  bf16_t* hbuf   = (bf16_t*)take((size_t)E_ * MP * DIM_ * 2);
  bf16_t* obuf   = (bf16_t*)take((size_t)E_ * MP * DIM_ * 2);  // q / attn out / W1 out
  float*  racc   = (float*)take((size_t)B_ * DIM_ * 4);
  float*  gws    = (float*)take((size_t)B_ * E_ * 4);
  float*  late   = (float*)take((size_t)E_ * B_ * DIM_ * 4);
  // union region:
  //   view A (dead after k_gemm_proj): x_bf / wr_t / wp_t
  //   view B (rewritten every (l,group)): zc-expert k (row-major) + v
  char* uni = (char*)w + off;
  bf16_t* x_bf = (bf16_t*)(uni);
  bf16_t* wr_t = (bf16_t*)(uni + (size_t)8192 * IN_ * 2);
  bf16_t* wp_t = (bf16_t*)(uni + (size_t)8192 * IN_ * 2 + (size_t)DIM_ * IN_ * 2);
  // pick expert-group width: all 4 experts if workspace allows, else pairs
  size_t kslice_b = (size_t)MP * DIM_ * 2;   // bytes per expert k (row-major)
  size_t vslice_b = KV_SLICE * 2;            // bytes per expert v
  size_t need_full = off + 4 * (kslice_b + vslice_b);
  int zc = (ws_size >= need_full) ? 4 : 2;
  bf16_t* kbuf = (bf16_t*)(uni);
  bf16_t* vbuf = (bf16_t*)(uni + (size_t)zc * kslice_b);
  (void)in_sizes; (void)n_in; (void)out_size;

  // input + weight conversion (weights transposed to [N][K] bf16)
  int n4 = 8192 * IN_ / 4;
  k_cvt<<<(n4 + 255) / 256, 256, 0, stream>>>(x, x_bf, n4);
  dim3 tb(32, 8);
  k_tcvt<<<dim3(DIM_ / 32, IN_ / 32, 1), tb, 0, stream>>>(Wr, wr_t, IN_, DIM_);
  k_tcvt<<<dim3(DIM_ / 32, IN_ / 32, E_), tb, 0, stream>>>(Wp, wp_t, IN_, DIM_);
  k_tcvt<<<dim3(3 * DIM_ / 32, DIM_ / 32, E_ * DEPTH_), tb, 0, stream>>>(Wqkv, wqkv_t, DIM_, 3 * DIM_);
  k_tcvt<<<dim3(DIM_ / 32, DIM_ / 32, E_ * DEPTH_), tb, 0, stream>>>(Wo, wo_t, DIM_, DIM_);
  k_tcvt<<<dim3(DIM_ / 32, DIM_ / 32, E_ * DEPTH_), tb, 0, stream>>>(W1, w1_t, DIM_, DIM_);
  k_tcvt<<<dim3(DIM_ / 32, DIM_ / 32, E_ * DEPTH_), tb, 0, stream>>>(W2, w2_t, DIM_, DIM_);

  // router + expert input projections (z=0 router-pool, z=1..4 experts)
  hipMemsetAsync(racc, 0, (size_t)B_ * DIM_ * 4, stream);
  k_gemm_proj<<<dim3(64, 4, 5), 256, 0, stream>>>(x_bf, wr_t, wp_t, br, bp, racc, tbuf);
  k_cls<<<32, 512, 0, stream>>>(cls, tbuf);
  k_router<<<1, 64, 0, stream>>>(racc, Wrf, brf, gws, out + B_ * DIM_ + B_ * C_);
  // zero v buffer once: its padded s-range [S_, SPK) is never written by the
  // v-GEMM but IS multiplied (by P=0) in attention -- must be finite.
  hipMemsetAsync(vbuf, 0, (size_t)zc * vslice_b, stream);

  for (int l = 0; l < DEPTH_; l++) {
    int last = (l == DEPTH_ - 1);
    k_ln<<<MROWS * E_ / 4, 256, 0, stream>>>(tbuf, ln1g, ln1b, l, hbuf);
    for (int eb = 0; eb < E_; eb += zc) {
      k_gemm_qkv<<<dim3(65, 12, zc), 256, 0, stream>>>(hbuf, wqkv_t, bqkv, eb, l, last,
                                                       obuf, kbuf, vbuf);
      k_attn<<<dim3(576 * zc, 1, 1), 256, 0, stream>>>(obuf, kbuf, vbuf, eb, last);
    }
    k_gemm_res<<<dim3(65, 4, E_), 256, 0, stream>>>(obuf, wo_t, bo, l, last, tbuf);
    k_ln<<<MROWS * E_ / 4, 256, 0, stream>>>(tbuf, ln2g, ln2b, l, hbuf);
    k_gemm_gelu<<<dim3(65, 4, E_), 256, 0, stream>>>(hbuf, w1_t, b1, l, last, obuf);
    k_gemm_res<<<dim3(65, 4, E_), 256, 0, stream>>>(obuf, w2_t, b2, l, last, tbuf);
  }
  k_lnf<<<32, 256, 0, stream>>>(tbuf, lnfg, lnfb, late);
  k_head<<<8, 256, 0, stream>>>(late, Wh, bh, gws, out);
}